// Round 1
// baseline (1524.955 us; speedup 1.0000x reference)
//
#include <hip/hip_runtime.h>
#include <math.h>

#define NB    4        // graphs
#define NN    8192     // coarse nodes
#define MM    65536    // fine nodes
#define EE    131072   // edges
#define NPG   2048     // coarse per graph
#define MPG   16384    // fine per graph
#define EPG   32768    // edges per graph

// ---------------------------------------------------------------------------
// knn_interpolate (k=3) + build h0 = [xf | x_skip], plus passthrough outputs
// ---------------------------------------------------------------------------
__global__ __launch_bounds__(256)
void k_knn(const float* __restrict__ pos, const float* __restrict__ pos_skip,
           const float* __restrict__ x, const float* __restrict__ x_skip,
           const int* __restrict__ batch_skip,
           float* __restrict__ h0, float* __restrict__ out_pos,
           float* __restrict__ out_batch)
{
    __shared__ float4 cp[NPG];                 // coarse (x,y,z,|p|^2)
    int g = blockIdx.x >> 6;                   // 64 blocks of 256 per graph
    int cbase = g * NPG;
    for (int c = threadIdx.x; c < NPG; c += 256) {
        float px = pos[(cbase + c) * 3 + 0];
        float py = pos[(cbase + c) * 3 + 1];
        float pz = pos[(cbase + c) * 3 + 2];
        cp[c] = make_float4(px, py, pz, px * px + py * py + pz * pz);
    }
    __syncthreads();

    int f = blockIdx.x * 256 + threadIdx.x;    // global fine node
    float fx = pos_skip[f * 3 + 0], fy = pos_skip[f * 3 + 1], fz = pos_skip[f * 3 + 2];
    float fq = fx * fx + fy * fy + fz * fz;

    float d0 = 3.4e38f, d1 = 3.4e38f, d2v = 3.4e38f;
    int i0 = 0, i1 = 0, i2 = 0;
    for (int c = 0; c < NPG; ++c) {
        float4 cc = cp[c];
        float d = (fq + cc.w) - 2.f * (fx * cc.x + fy * cc.y + fz * cc.z);
        if (d < d2v) {
            if (d < d1) {
                d2v = d1; i2 = i1;
                if (d < d0) { d1 = d0; i1 = i0; d0 = d; i0 = c; }
                else        { d1 = d;  i1 = c; }
            } else { d2v = d; i2 = c; }
        }
    }
    float w0 = 1.f / fmaxf(d0, 1e-16f);
    float w1 = 1.f / fmaxf(d1, 1e-16f);
    float w2 = 1.f / fmaxf(d2v, 1e-16f);
    float wsum = w0 + w1 + w2;

    const float4* x4 = (const float4*)x;
    float4* h04 = (float4*)(h0 + (size_t)f * 32);
    int a0 = (cbase + i0) * 4, a1 = (cbase + i1) * 4, a2 = (cbase + i2) * 4;
#pragma unroll
    for (int j = 0; j < 4; ++j) {
        float4 v0 = x4[a0 + j], v1 = x4[a1 + j], v2 = x4[a2 + j];
        float4 r;
        r.x = (w0 * v0.x + w1 * v1.x + w2 * v2.x) / wsum;
        r.y = (w0 * v0.y + w1 * v1.y + w2 * v2.y) / wsum;
        r.z = (w0 * v0.z + w1 * v1.z + w2 * v2.z) / wsum;
        r.w = (w0 * v0.w + w1 * v1.w + w2 * v2.w) / wsum;
        h04[j] = r;
    }
    const float4* xs4 = (const float4*)x_skip;
#pragma unroll
    for (int j = 0; j < 4; ++j) h04[4 + j] = xs4[f * 4 + j];

    out_pos[f * 3 + 0] = fx; out_pos[f * 3 + 1] = fy; out_pos[f * 3 + 2] = fz;
    out_batch[f] = (float)batch_skip[f];
}

// ---------------------------------------------------------------------------
// token prep 1: Kt/Vt = gt @ W^T + b + pe   -> KtVt [B][2][16][64]
// ---------------------------------------------------------------------------
__global__ __launch_bounds__(128)
void k_tokens1(const float* __restrict__ gt,
               const float* __restrict__ Wk_w, const float* __restrict__ Wk_b,
               const float* __restrict__ Wv_w, const float* __restrict__ Wv_b,
               float* __restrict__ KtVt)
{
    int b = blockIdx.x >> 4;
    int t = blockIdx.x & 15;
    int which = threadIdx.x >> 6;      // 0 = K, 1 = V
    int d = threadIdx.x & 63;
    const float* W = which ? Wv_w : Wk_w;
    const float* bias = which ? Wv_b : Wk_b;
    const float4* row = (const float4*)(gt + (size_t)(b * 16 + t) * 1024);
    const float4* wr = (const float4*)(W + (size_t)d * 1024);
    float acc = 0.f;
    for (int c = 0; c < 256; ++c) {
        float4 a = row[c], w = wr[c];
        acc += a.x * w.x; acc += a.y * w.y; acc += a.z * w.z; acc += a.w * w.w;
    }
    int i2 = d >> 1;
    float dv = expf((float)(2 * i2) * (-0.14391156831212787f)); // -ln(10000)/64
    float ang = (float)t * dv;
    float pe = (d & 1) ? cosf(ang) : sinf(ang);
    KtVt[((size_t)(b * 2 + which) * 16 + t) * 64 + d] = acc + bias[d] + pe;
}

// ---------------------------------------------------------------------------
// token prep 2: k heads, V2 = out_w-folded v heads, qW/qb2 fold
// ---------------------------------------------------------------------------
__global__ __launch_bounds__(256)
void k_tokens2(const float* __restrict__ KtVt,
               const float* __restrict__ in_proj_w, const float* __restrict__ in_proj_b,
               const float* __restrict__ out_w,
               const float* __restrict__ Wq_w, const float* __restrict__ Wq_b,
               float* __restrict__ kall, float* __restrict__ V2,
               float* __restrict__ qW, float* __restrict__ qb2)
{
    int b = blockIdx.x;
    __shared__ float KtL[1024], VtL[1024], vv[1024];
    for (int idx = threadIdx.x; idx < 1024; idx += 256) {
        KtL[idx] = KtVt[(size_t)(b * 2 + 0) * 1024 + idx];
        VtL[idx] = KtVt[(size_t)(b * 2 + 1) * 1024 + idx];
    }
    __syncthreads();
    for (int idx = threadIdx.x; idx < 2048; idx += 256) {
        int which = idx >> 10; int td = idx & 1023; int t = td >> 6; int j = td & 63;
        int r = (which ? 128 : 64) + j;
        const float* w = in_proj_w + (size_t)r * 64;
        const float* src = which ? VtL : KtL;
        float acc = in_proj_b[r];
#pragma unroll 8
        for (int dd = 0; dd < 64; ++dd) acc += src[t * 64 + dd] * w[dd];
        if (which) vv[t * 64 + j] = acc;
        else kall[(size_t)(b * 16 + t) * 64 + j] = acc;
    }
    __syncthreads();
    for (int idx = threadIdx.x; idx < 4096; idx += 256) {
        int jo = idx & 63; int th = idx >> 6; int h = th & 3; int t = th >> 2;
        float acc = 0.f;
#pragma unroll
        for (int dd = 0; dd < 16; ++dd)
            acc += vv[t * 64 + h * 16 + dd] * out_w[(size_t)jo * 64 + h * 16 + dd];
        V2[(((size_t)(b * 16 + t)) * 4 + h) * 64 + jo] = acc;
    }
    if (b == 0) {
        for (int idx = threadIdx.x; idx < 192; idx += 256) {
            int c = idx >> 6; int j = idx & 63;
            float acc = 0.f;
            for (int dd = 0; dd < 64; ++dd) acc += in_proj_w[(size_t)j * 64 + dd] * Wq_w[dd * 3 + c];
            qW[c * 64 + j] = acc;
        }
        for (int j = threadIdx.x; j < 64; j += 256) {
            float acc = in_proj_b[j];
            for (int dd = 0; dd < 64; ++dd) acc += in_proj_w[(size_t)j * 64 + dd] * Wq_b[dd];
            qb2[j] = acc;
        }
    }
}

// ---------------------------------------------------------------------------
// per-edge cross attention -> pseudoF rows [E][68] = [dx,dy,dz, attn_out(64), 0]
// ---------------------------------------------------------------------------
__global__ __launch_bounds__(256)
void k_edge_attn(const float* __restrict__ ps, const int* __restrict__ ei,
                 const float* __restrict__ kall, const float* __restrict__ V2g,
                 const float* __restrict__ qW, const float* __restrict__ qb2,
                 const float* __restrict__ ob,
                 float* __restrict__ pF)
{
    __shared__ __align__(16) float kk[1024];
    __shared__ __align__(16) float v2s[4096];
    __shared__ float qWs[192];
    __shared__ float qbs[64];
    __shared__ __align__(16) float obs[64];
    int g = blockIdx.x >> 7;       // 128 blocks of 256 edges per graph
    for (int idx = threadIdx.x; idx < 1024; idx += 256) kk[idx] = kall[(size_t)g * 1024 + idx];
    for (int idx = threadIdx.x; idx < 4096; idx += 256) v2s[idx] = V2g[(size_t)g * 4096 + idx];
    if (threadIdx.x < 192) qWs[threadIdx.x] = qW[threadIdx.x];
    if (threadIdx.x < 64) { qbs[threadIdx.x] = qb2[threadIdx.x]; obs[threadIdx.x] = ob[threadIdx.x]; }
    __syncthreads();

    int e = blockIdx.x * 256 + threadIdx.x;
    int s = ei[e], d = ei[EE + e];
    float sx = ps[s * 3], sy = ps[s * 3 + 1], sz = ps[s * 3 + 2];
    float dx = ps[d * 3], dy = ps[d * 3 + 1], dz = ps[d * 3 + 2];
    float px = dx - sx, py = dy - sy, pz = dz - sz;
    float ex = 0.5f * (dx + sx), ey = 0.5f * (dy + sy), ez = 0.5f * (dz + sz);

    float att[4][16];
    const float4* kk4 = (const float4*)kk;
#pragma unroll
    for (int h = 0; h < 4; ++h) {
        float qh[16];
#pragma unroll
        for (int dd = 0; dd < 16; ++dd) {
            int j = h * 16 + dd;
            qh[dd] = qbs[j] + ex * qWs[j] + ey * qWs[64 + j] + ez * qWs[128 + j];
        }
        float sc[16]; float mx = -3.4e38f;
#pragma unroll
        for (int t = 0; t < 16; ++t) {
            float a = 0.f;
#pragma unroll
            for (int qd = 0; qd < 4; ++qd) {
                float4 kv = kk4[t * 16 + h * 4 + qd];
                a += qh[qd * 4 + 0] * kv.x; a += qh[qd * 4 + 1] * kv.y;
                a += qh[qd * 4 + 2] * kv.z; a += qh[qd * 4 + 3] * kv.w;
            }
            a *= 0.25f;               // 1/sqrt(hd)
            sc[t] = a; mx = fmaxf(mx, a);
        }
        float ssum = 0.f;
#pragma unroll
        for (int t = 0; t < 16; ++t) { float eo = expf(sc[t] - mx); sc[t] = eo; ssum += eo; }
        float inv = 1.f / ssum;
#pragma unroll
        for (int t = 0; t < 16; ++t) att[h][t] = sc[t] * inv;
    }

    float* orow = pF + (size_t)e * 68;
    orow[0] = px; orow[1] = py; orow[2] = pz;
    const float4* v24 = (const float4*)v2s;
    for (int q = 0; q < 16; ++q) {
        float4 acc = ((const float4*)obs)[q];
#pragma unroll
        for (int t = 0; t < 16; ++t)
#pragma unroll
            for (int h = 0; h < 4; ++h) {
                float a = att[h][t];
                float4 vq = v24[(t * 4 + h) * 16 + q];
                acc.x += a * vq.x; acc.y += a * vq.y; acc.z += a * vq.z; acc.w += a * vq.w;
            }
        orow[3 + q * 4 + 0] = acc.x; orow[3 + q * 4 + 1] = acc.y;
        orow[3 + q * 4 + 2] = acc.z; orow[3 + q * 4 + 3] = acc.w;
    }
    orow[67] = 0.f;
}

// ---------------------------------------------------------------------------
// degree count / reciprocal
// ---------------------------------------------------------------------------
__global__ __launch_bounds__(256)
void k_count(const int* __restrict__ ei, float* __restrict__ cnt)
{
    int e = blockIdx.x * 256 + threadIdx.x;
    atomicAdd(&cnt[ei[EE + e]], 1.f);
}

__global__ __launch_bounds__(256)
void k_inv(float* __restrict__ cnt)
{
    int v = blockIdx.x * 256 + threadIdx.x;
    cnt[v] = 1.f / fmaxf(cnt[v], 1.f);
}

// ---------------------------------------------------------------------------
// repack nn_w [rows][67] -> padded [rows][68] (pad col = 0)
// ---------------------------------------------------------------------------
__global__ __launch_bounds__(256)
void k_repack(const float* __restrict__ nw, float* __restrict__ nwP, int rows)
{
    int idx = blockIdx.x * 256 + threadIdx.x;
    if (idx >= rows * 68) return;
    int r = idx / 68, c = idx % 68;
    nwP[idx] = (c < 67) ? nw[(size_t)r * 67 + c] : 0.f;
}

// ---------------------------------------------------------------------------
// fused NNConv edge pass: we = relu(p @ nw^T + nb); msg = h[src] . we ;
// atomic scatter into aggr.  4x4 register tile per thread, strided e/o maps.
// ---------------------------------------------------------------------------
template<int CO, int TE>
__global__ __launch_bounds__(128)
void k_conv_edge(const float* __restrict__ pF, const float* __restrict__ hin,
                 const int* __restrict__ ei, const float* __restrict__ nwP,
                 const float* __restrict__ nb, float* __restrict__ aggr)
{
    constexpr int OT = CO / 4;
    constexpr int ET = TE / 4;
    constexpr int NT = OT * ET;                  // 128 threads
    __shared__ float4 pL[TE * 17];               // pseudo rows (68 floats)
    __shared__ float4 wL[CO * 17];               // weight rows for current i
    __shared__ float  hL[TE][33];                // gathered h[src], +1 pad
    __shared__ int    sL[TE];
    __shared__ int    dL[TE];
    __shared__ float  nbL[CO];

    int tid = threadIdx.x;
    int e0 = blockIdx.x * TE;
    if (tid < TE) { sL[tid] = ei[e0 + tid]; dL[tid] = ei[EE + e0 + tid]; }
    __syncthreads();

    const float4* pg = (const float4*)pF + (size_t)e0 * 17;
    for (int idx = tid; idx < TE * 17; idx += NT) pL[idx] = pg[idx];
    for (int idx = tid; idx < TE * 32; idx += NT) {
        int e = idx >> 5, j = idx & 31;
        hL[e][j] = hin[(size_t)sL[e] * 32 + j];
    }
    __syncthreads();

    int ot = tid % OT, et = tid / OT;
    float msg[4][4];
#pragma unroll
    for (int a = 0; a < 4; ++a)
#pragma unroll
        for (int b = 0; b < 4; ++b) msg[a][b] = 0.f;

    for (int i = 0; i < 32; ++i) {
        const float4* wg = (const float4*)nwP + (size_t)(i * CO) * 17;
        for (int idx = tid; idx < CO * 17; idx += NT) wL[idx] = wg[idx];
        if (tid < CO) nbL[tid] = nb[i * CO + tid];
        __syncthreads();

        float we[4][4];
#pragma unroll
        for (int ee = 0; ee < 4; ++ee)
#pragma unroll
            for (int oo = 0; oo < 4; ++oo) we[ee][oo] = nbL[ot + oo * OT];

#pragma unroll
        for (int j4 = 0; j4 < 17; ++j4) {
            float4 pr[4], wr[4];
#pragma unroll
            for (int ee = 0; ee < 4; ++ee) pr[ee] = pL[(et + ee * ET) * 17 + j4];
#pragma unroll
            for (int oo = 0; oo < 4; ++oo) wr[oo] = wL[(ot + oo * OT) * 17 + j4];
#pragma unroll
            for (int ee = 0; ee < 4; ++ee)
#pragma unroll
                for (int oo = 0; oo < 4; ++oo) {
                    we[ee][oo] += pr[ee].x * wr[oo].x;
                    we[ee][oo] += pr[ee].y * wr[oo].y;
                    we[ee][oo] += pr[ee].z * wr[oo].z;
                    we[ee][oo] += pr[ee].w * wr[oo].w;
                }
        }
#pragma unroll
        for (int ee = 0; ee < 4; ++ee) {
            float hv = hL[et + ee * ET][i];
#pragma unroll
            for (int oo = 0; oo < 4; ++oo) msg[ee][oo] += hv * fmaxf(we[ee][oo], 0.f);
        }
        __syncthreads();
    }

#pragma unroll
    for (int ee = 0; ee < 4; ++ee) {
        int dv = dL[et + ee * ET];
#pragma unroll
        for (int oo = 0; oo < 4; ++oo)
            atomicAdd(&aggr[(size_t)dv * CO + ot + oo * OT], msg[ee][oo]);
    }
}

// ---------------------------------------------------------------------------
// node update: h' = relu(aggr/cnt + h @ root + bias)
// ---------------------------------------------------------------------------
template<int CO>
__global__ __launch_bounds__(256)
void k_update(const float* __restrict__ aggr, const float* __restrict__ cntInv,
              const float* __restrict__ hin, const float* __restrict__ root,
              const float* __restrict__ bias, float* __restrict__ hout)
{
    __shared__ float rL[32 * CO];
    __shared__ float bL[CO];
    int tid = threadIdx.x;
    for (int idx = tid; idx < 32 * CO; idx += 256) rL[idx] = root[idx];
    if (tid < CO) bL[tid] = bias[tid];
    __syncthreads();
    int gid = blockIdx.x * 256 + tid;
    int v = gid / CO;
    int o = gid % CO;
    float acc = aggr[gid] * cntInv[v] + bL[o];
    const float* hr = hin + (size_t)v * 32;
#pragma unroll
    for (int i = 0; i < 32; ++i) acc += hr[i] * rL[i * CO + o];
    hout[gid] = fmaxf(acc, 0.f);
}

// ---------------------------------------------------------------------------
extern "C" void kernel_launch(void* const* d_in, const int* in_sizes, int n_in,
                              void* d_out, int out_size, void* d_ws, size_t ws_size,
                              hipStream_t stream)
{
    const float* x          = (const float*)d_in[0];
    const float* pos        = (const float*)d_in[1];
    const float* x_skip     = (const float*)d_in[3];
    const float* pos_skip   = (const float*)d_in[4];
    const int*   batch_skip = (const int*)  d_in[5];
    const int*   ei         = (const int*)  d_in[6];
    const float* gt         = (const float*)d_in[7];
    const float* Wq_w       = (const float*)d_in[8];
    const float* Wq_b       = (const float*)d_in[9];
    const float* Wk_w       = (const float*)d_in[10];
    const float* Wk_b       = (const float*)d_in[11];
    const float* Wv_w       = (const float*)d_in[12];
    const float* Wv_b       = (const float*)d_in[13];
    const float* in_proj_w  = (const float*)d_in[14];
    const float* in_proj_b  = (const float*)d_in[15];
    const float* out_w      = (const float*)d_in[16];
    const float* out_b      = (const float*)d_in[17];
    const float* nn_w0 = (const float*)d_in[18]; const float* nn_b0 = (const float*)d_in[19];
    const float* root0 = (const float*)d_in[20]; const float* bias0 = (const float*)d_in[21];
    const float* nn_w1 = (const float*)d_in[22]; const float* nn_b1 = (const float*)d_in[23];
    const float* root1 = (const float*)d_in[24]; const float* bias1 = (const float*)d_in[25];
    const float* nn_w2 = (const float*)d_in[26]; const float* nn_b2 = (const float*)d_in[27];
    const float* root2 = (const float*)d_in[28]; const float* bias2 = (const float*)d_in[29];

    float* ws = (float*)d_ws;
    size_t off = 0;
    float* hA   = ws + off; off += (size_t)MM * 32;
    float* hB   = ws + off; off += (size_t)MM * 32;
    float* aggr = ws + off; off += (size_t)MM * 32;
    float* pF   = ws + off; off += (size_t)EE * 68;
    float* cnt  = ws + off; off += MM;
    float* kall = ws + off; off += NB * 16 * 64;
    float* V2   = ws + off; off += NB * 16 * 4 * 64;
    float* qW   = ws + off; off += 192;
    float* qb2  = ws + off; off += 64;
    float* KtVt = ws + off; off += NB * 2 * 16 * 64;
    float* nwP0 = ws + off; off += 1024 * 68;
    float* nwP1 = ws + off; off += 1024 * 68;
    float* nwP2 = ws + off; off += 512 * 68;

    float* h_final   = (float*)d_out;                 // [M,16]
    float* out_pos   = (float*)d_out + (size_t)MM * 16;
    float* out_batch = (float*)d_out + (size_t)MM * 19;

    hipMemsetAsync(cnt, 0, (size_t)MM * sizeof(float), stream);

    k_tokens1<<<64, 128, 0, stream>>>(gt, Wk_w, Wk_b, Wv_w, Wv_b, KtVt);
    k_tokens2<<<NB, 256, 0, stream>>>(KtVt, in_proj_w, in_proj_b, out_w, Wq_w, Wq_b,
                                      kall, V2, qW, qb2);
    k_knn<<<MM / 256, 256, 0, stream>>>(pos, pos_skip, x, x_skip, batch_skip,
                                        hA, out_pos, out_batch);
    k_edge_attn<<<EE / 256, 256, 0, stream>>>(pos_skip, ei, kall, V2, qW, qb2, out_b, pF);
    k_count<<<EE / 256, 256, 0, stream>>>(ei, cnt);
    k_inv<<<MM / 256, 256, 0, stream>>>(cnt);
    k_repack<<<(1024 * 68) / 256, 256, 0, stream>>>(nn_w0, nwP0, 1024);
    k_repack<<<(1024 * 68) / 256, 256, 0, stream>>>(nn_w1, nwP1, 1024);
    k_repack<<<(512 * 68) / 256, 256, 0, stream>>>(nn_w2, nwP2, 512);

    // layer 0: hA -> hB
    hipMemsetAsync(aggr, 0, (size_t)MM * 32 * sizeof(float), stream);
    k_conv_edge<32, 64><<<EE / 64, 128, 0, stream>>>(pF, hA, ei, nwP0, nn_b0, aggr);
    k_update<32><<<(MM * 32) / 256, 256, 0, stream>>>(aggr, cnt, hA, root0, bias0, hB);
    // layer 1: hB -> hA
    hipMemsetAsync(aggr, 0, (size_t)MM * 32 * sizeof(float), stream);
    k_conv_edge<32, 64><<<EE / 64, 128, 0, stream>>>(pF, hB, ei, nwP1, nn_b1, aggr);
    k_update<32><<<(MM * 32) / 256, 256, 0, stream>>>(aggr, cnt, hB, root1, bias1, hA);
    // layer 2: hA -> d_out
    hipMemsetAsync(aggr, 0, (size_t)MM * 16 * sizeof(float), stream);
    k_conv_edge<16, 128><<<EE / 128, 128, 0, stream>>>(pF, hA, ei, nwP2, nn_b2, aggr);
    k_update<16><<<(MM * 16) / 256, 256, 0, stream>>>(aggr, cnt, hA, root2, bias2, h_final);
}

// Round 2
// 575.812 us; speedup vs baseline: 2.6484x; 2.6484x over previous
//
#include <hip/hip_runtime.h>
#include <math.h>

#define NB    4        // graphs
#define NN    8192     // coarse nodes
#define MM    65536    // fine nodes
#define EE    131072   // edges
#define NPG   2048     // coarse per graph

typedef short short8 __attribute__((ext_vector_type(8)));
typedef float f32x4  __attribute__((ext_vector_type(4)));

static __device__ inline unsigned short f2b(float f) {
    unsigned u = __float_as_uint(f);
    u += 0x7fffu + ((u >> 16) & 1u);           // RNE
    return (unsigned short)(u >> 16);
}
static __device__ inline unsigned f2b_pack(float a, float b) {
    unsigned x = __float_as_uint(a); x += 0x7fffu + ((x >> 16) & 1u);
    unsigned y = __float_as_uint(b); y += 0x7fffu + ((y >> 16) & 1u);
    return (x >> 16) | (y & 0xffff0000u);
}
static __device__ inline short8 bc8(uint4 v) {
    union { uint4 u; short8 s; } c; c.u = v; return c.s;
}

// ---------------------------------------------------------------------------
// knn_interpolate (k=3) + build h0 = [xf | x_skip], plus passthrough outputs
// ---------------------------------------------------------------------------
__global__ __launch_bounds__(256)
void k_knn(const float* __restrict__ pos, const float* __restrict__ pos_skip,
           const float* __restrict__ x, const float* __restrict__ x_skip,
           const int* __restrict__ batch_skip,
           float* __restrict__ h0, float* __restrict__ out_pos,
           float* __restrict__ out_batch)
{
    __shared__ float4 cp[NPG];                 // coarse (x,y,z,|p|^2)
    int g = blockIdx.x >> 6;
    int cbase = g * NPG;
    for (int c = threadIdx.x; c < NPG; c += 256) {
        float px = pos[(cbase + c) * 3 + 0];
        float py = pos[(cbase + c) * 3 + 1];
        float pz = pos[(cbase + c) * 3 + 2];
        cp[c] = make_float4(px, py, pz, px * px + py * py + pz * pz);
    }
    __syncthreads();

    int f = blockIdx.x * 256 + threadIdx.x;
    float fx = pos_skip[f * 3 + 0], fy = pos_skip[f * 3 + 1], fz = pos_skip[f * 3 + 2];
    float fq = fx * fx + fy * fy + fz * fz;

    float d0 = 3.4e38f, d1 = 3.4e38f, d2v = 3.4e38f;
    int i0 = 0, i1 = 0, i2 = 0;
    for (int c = 0; c < NPG; ++c) {
        float4 cc = cp[c];
        float d = (fq + cc.w) - 2.f * (fx * cc.x + fy * cc.y + fz * cc.z);
        if (d < d2v) {
            if (d < d1) {
                d2v = d1; i2 = i1;
                if (d < d0) { d1 = d0; i1 = i0; d0 = d; i0 = c; }
                else        { d1 = d;  i1 = c; }
            } else { d2v = d; i2 = c; }
        }
    }
    float w0 = 1.f / fmaxf(d0, 1e-16f);
    float w1 = 1.f / fmaxf(d1, 1e-16f);
    float w2 = 1.f / fmaxf(d2v, 1e-16f);
    float wsum = w0 + w1 + w2;

    const float4* x4 = (const float4*)x;
    float4* h04 = (float4*)(h0 + (size_t)f * 32);
    int a0 = (cbase + i0) * 4, a1 = (cbase + i1) * 4, a2 = (cbase + i2) * 4;
#pragma unroll
    for (int j = 0; j < 4; ++j) {
        float4 v0 = x4[a0 + j], v1 = x4[a1 + j], v2 = x4[a2 + j];
        float4 r;
        r.x = (w0 * v0.x + w1 * v1.x + w2 * v2.x) / wsum;
        r.y = (w0 * v0.y + w1 * v1.y + w2 * v2.y) / wsum;
        r.z = (w0 * v0.z + w1 * v1.z + w2 * v2.z) / wsum;
        r.w = (w0 * v0.w + w1 * v1.w + w2 * v2.w) / wsum;
        h04[j] = r;
    }
    const float4* xs4 = (const float4*)x_skip;
#pragma unroll
    for (int j = 0; j < 4; ++j) h04[4 + j] = xs4[f * 4 + j];

    out_pos[f * 3 + 0] = fx; out_pos[f * 3 + 1] = fy; out_pos[f * 3 + 2] = fz;
    out_batch[f] = (float)batch_skip[f];
}

// ---------------------------------------------------------------------------
// token prep 1: Kt/Vt = gt @ W^T + b + pe   -> KtVt [B][2][16][64]
// ---------------------------------------------------------------------------
__global__ __launch_bounds__(128)
void k_tokens1(const float* __restrict__ gt,
               const float* __restrict__ Wk_w, const float* __restrict__ Wk_b,
               const float* __restrict__ Wv_w, const float* __restrict__ Wv_b,
               float* __restrict__ KtVt)
{
    int b = blockIdx.x >> 4;
    int t = blockIdx.x & 15;
    int which = threadIdx.x >> 6;
    int d = threadIdx.x & 63;
    const float* W = which ? Wv_w : Wk_w;
    const float* bias = which ? Wv_b : Wk_b;
    const float4* row = (const float4*)(gt + (size_t)(b * 16 + t) * 1024);
    const float4* wr = (const float4*)(W + (size_t)d * 1024);
    float acc = 0.f;
    for (int c = 0; c < 256; ++c) {
        float4 a = row[c], w = wr[c];
        acc += a.x * w.x; acc += a.y * w.y; acc += a.z * w.z; acc += a.w * w.w;
    }
    int i2 = d >> 1;
    float dv = expf((float)(2 * i2) * (-0.14391156831212787f)); // -ln(10000)/64
    float ang = (float)t * dv;
    float pe = (d & 1) ? cosf(ang) : sinf(ang);
    KtVt[((size_t)(b * 2 + which) * 16 + t) * 64 + d] = acc + bias[d] + pe;
}

// ---------------------------------------------------------------------------
// token prep 2: k heads, V2 = out_w-folded v heads, qW/qb2 fold
// ---------------------------------------------------------------------------
__global__ __launch_bounds__(256)
void k_tokens2(const float* __restrict__ KtVt,
               const float* __restrict__ in_proj_w, const float* __restrict__ in_proj_b,
               const float* __restrict__ out_w,
               const float* __restrict__ Wq_w, const float* __restrict__ Wq_b,
               float* __restrict__ kall, float* __restrict__ V2,
               float* __restrict__ qW, float* __restrict__ qb2)
{
    int b = blockIdx.x;
    __shared__ float KtL[1024], VtL[1024], vv[1024];
    for (int idx = threadIdx.x; idx < 1024; idx += 256) {
        KtL[idx] = KtVt[(size_t)(b * 2 + 0) * 1024 + idx];
        VtL[idx] = KtVt[(size_t)(b * 2 + 1) * 1024 + idx];
    }
    __syncthreads();
    for (int idx = threadIdx.x; idx < 2048; idx += 256) {
        int which = idx >> 10; int td = idx & 1023; int t = td >> 6; int j = td & 63;
        int r = (which ? 128 : 64) + j;
        const float* w = in_proj_w + (size_t)r * 64;
        const float* src = which ? VtL : KtL;
        float acc = in_proj_b[r];
#pragma unroll 8
        for (int dd = 0; dd < 64; ++dd) acc += src[t * 64 + dd] * w[dd];
        if (which) vv[t * 64 + j] = acc;
        else kall[(size_t)(b * 16 + t) * 64 + j] = acc;
    }
    __syncthreads();
    for (int idx = threadIdx.x; idx < 4096; idx += 256) {
        int jo = idx & 63; int th = idx >> 6; int h = th & 3; int t = th >> 2;
        float acc = 0.f;
#pragma unroll
        for (int dd = 0; dd < 16; ++dd)
            acc += vv[t * 64 + h * 16 + dd] * out_w[(size_t)jo * 64 + h * 16 + dd];
        V2[(((size_t)(b * 16 + t)) * 4 + h) * 64 + jo] = acc;
    }
    if (b == 0) {
        for (int idx = threadIdx.x; idx < 192; idx += 256) {
            int c = idx >> 6; int j = idx & 63;
            float acc = 0.f;
            for (int dd = 0; dd < 64; ++dd) acc += in_proj_w[(size_t)j * 64 + dd] * Wq_w[dd * 3 + c];
            qW[c * 64 + j] = acc;
        }
        for (int j = threadIdx.x; j < 64; j += 256) {
            float acc = in_proj_b[j];
            for (int dd = 0; dd < 64; ++dd) acc += in_proj_w[(size_t)j * 64 + dd] * Wq_b[dd];
            qb2[j] = acc;
        }
    }
}

// ---------------------------------------------------------------------------
// per-edge cross attention -> Pf in bf16 A-fragment order, K padded to 96:
//   k 0..63  = attn out, k 64..66 = (px,py,pz), k 67 = 1.0 (bias), 68..95 = 0
// Pf flat layout: [(et*3 + step)*64 + lane] * 8 shorts, lane = quad*16 + (e&15),
// k = step*32 + quad*8 + jj   (A-frag mapping A[m=lane&15][k=quad*8+j])
// ---------------------------------------------------------------------------
__global__ __launch_bounds__(256)
void k_edge_attn(const float* __restrict__ ps, const int* __restrict__ ei,
                 const float* __restrict__ kall, const float* __restrict__ V2g,
                 const float* __restrict__ qW, const float* __restrict__ qb2,
                 const float* __restrict__ ob,
                 unsigned short* __restrict__ Pf)
{
    __shared__ __align__(16) float kk[1024];
    __shared__ __align__(16) float v2s[4096];
    __shared__ float qWs[192];
    __shared__ float qbs[64];
    __shared__ __align__(16) float obs[64];
    int g = blockIdx.x >> 7;
    for (int idx = threadIdx.x; idx < 1024; idx += 256) kk[idx] = kall[(size_t)g * 1024 + idx];
    for (int idx = threadIdx.x; idx < 4096; idx += 256) v2s[idx] = V2g[(size_t)g * 4096 + idx];
    if (threadIdx.x < 192) qWs[threadIdx.x] = qW[threadIdx.x];
    if (threadIdx.x < 64) { qbs[threadIdx.x] = qb2[threadIdx.x]; obs[threadIdx.x] = ob[threadIdx.x]; }
    __syncthreads();

    int e = blockIdx.x * 256 + threadIdx.x;
    int s = ei[e], d = ei[EE + e];
    float sx = ps[s * 3], sy = ps[s * 3 + 1], sz = ps[s * 3 + 2];
    float dx = ps[d * 3], dy = ps[d * 3 + 1], dz = ps[d * 3 + 2];
    float px = dx - sx, py = dy - sy, pz = dz - sz;
    float ex = 0.5f * (dx + sx), ey = 0.5f * (dy + sy), ez = 0.5f * (dz + sz);

    float att[4][16];
    const float4* kk4 = (const float4*)kk;
#pragma unroll
    for (int h = 0; h < 4; ++h) {
        float qh[16];
#pragma unroll
        for (int dd = 0; dd < 16; ++dd) {
            int j = h * 16 + dd;
            qh[dd] = qbs[j] + ex * qWs[j] + ey * qWs[64 + j] + ez * qWs[128 + j];
        }
        float sc[16]; float mx = -3.4e38f;
#pragma unroll
        for (int t = 0; t < 16; ++t) {
            float a = 0.f;
#pragma unroll
            for (int qd = 0; qd < 4; ++qd) {
                float4 kv = kk4[t * 16 + h * 4 + qd];
                a += qh[qd * 4 + 0] * kv.x; a += qh[qd * 4 + 1] * kv.y;
                a += qh[qd * 4 + 2] * kv.z; a += qh[qd * 4 + 3] * kv.w;
            }
            a *= 0.25f;
            sc[t] = a; mx = fmaxf(mx, a);
        }
        float ssum = 0.f;
#pragma unroll
        for (int t = 0; t < 16; ++t) { float eo = expf(sc[t] - mx); sc[t] = eo; ssum += eo; }
        float inv = 1.f / ssum;
#pragma unroll
        for (int t = 0; t < 16; ++t) att[h][t] = sc[t] * inv;
    }

    int et = e >> 4, eL = e & 15;
    const float4* v24 = (const float4*)v2s;
#pragma unroll
    for (int q = 0; q < 16; ++q) {
        float4 acc = ((const float4*)obs)[q];
#pragma unroll
        for (int t = 0; t < 16; ++t)
#pragma unroll
            for (int h = 0; h < 4; ++h) {
                float a = att[h][t];
                float4 vq = v24[(t * 4 + h) * 16 + q];
                acc.x += a * vq.x; acc.y += a * vq.y; acc.z += a * vq.z; acc.w += a * vq.w;
            }
        int k0 = q * 4;
        int st = k0 >> 5, quad = (k0 >> 3) & 3, jj = k0 & 7;
        size_t base = ((size_t)(et * 3 + st) * 64 + quad * 16 + eL) * 8 + jj;
        uint2 v; v.x = f2b_pack(acc.x, acc.y); v.y = f2b_pack(acc.z, acc.w);
        *(uint2*)(Pf + base) = v;
    }
    // tail: step 2 (k = 64..95)
    size_t tb = ((size_t)(et * 3 + 2) * 64 + 0 * 16 + eL) * 8;
    uint2 t0; t0.x = f2b_pack(px, py); t0.y = f2b_pack(pz, 1.0f);
    *(uint2*)(Pf + tb) = t0;
    uint2 z2; z2.x = 0u; z2.y = 0u;
    *(uint2*)(Pf + tb + 4) = z2;
#pragma unroll
    for (int quad = 1; quad < 4; ++quad) {
        size_t zb = ((size_t)(et * 3 + 2) * 64 + quad * 16 + eL) * 8;
        uint4 z4; z4.x = 0u; z4.y = 0u; z4.z = 0u; z4.w = 0u;
        *(uint4*)(Pf + zb) = z4;
    }
}

// ---------------------------------------------------------------------------
// degree count / reciprocal
// ---------------------------------------------------------------------------
__global__ __launch_bounds__(256)
void k_count(const int* __restrict__ ei, float* __restrict__ cnt)
{
    int e = blockIdx.x * 256 + threadIdx.x;
    atomicAdd(&cnt[ei[EE + e]], 1.f);
}

__global__ __launch_bounds__(256)
void k_inv(float* __restrict__ cnt)
{
    int v = blockIdx.x * 256 + threadIdx.x;
    cnt[v] = 1.f / fmaxf(cnt[v], 1.f);
}

// ---------------------------------------------------------------------------
// repack nn_w [rows][67] + nn_b -> bf16 B-fragment stream Wf
// Wf[((jt*3+s)*64 + lane)*8 + jj] = Wpad[jt*16 + (lane&15)][s*32 + (lane>>4)*8 + jj]
// Wpad[j][k]: k<64 -> nw[j][3+k]; k in 64..66 -> nw[j][k-64]; k==67 -> nb[j]; else 0
// ---------------------------------------------------------------------------
__global__ __launch_bounds__(256)
void k_repackW(const float* __restrict__ nw, const float* __restrict__ nb,
               unsigned short* __restrict__ Wf, int total)
{
    int idx = blockIdx.x * 256 + threadIdx.x;
    if (idx >= total) return;
    int jj = idx & 7;
    int lane = (idx >> 3) & 63;
    int rest = idx >> 9;
    int s = rest % 3;
    int jt = rest / 3;
    int j = jt * 16 + (lane & 15);
    int k = s * 32 + (lane >> 4) * 8 + jj;
    float v;
    if (k < 64)       v = nw[(size_t)j * 67 + 3 + k];
    else if (k < 67)  v = nw[(size_t)j * 67 + (k - 64)];
    else if (k == 67) v = nb[j];
    else              v = 0.f;
    Wf[idx] = f2b(v);
}

// ---------------------------------------------------------------------------
// MFMA edge pass: per wave 32 edges (2 A-frag sets), loop 2*CO j-tiles:
//   we_tile = relu(P @ W^T) via 3x mfma_16x16x32_bf16; msg += h[src][i]*we;
// scatter atomicAdd at the end. No __syncthreads in the j-loop.
// ---------------------------------------------------------------------------
template<int CO>
__global__ __launch_bounds__(256, 4)
void k_conv_mfma(const uint4* __restrict__ Pf, const float* __restrict__ hin,
                 const int* __restrict__ ei, const uint4* __restrict__ Wf,
                 float* __restrict__ aggr)
{
    constexpr int JT = 2 * CO;          // 64 (CO=32) or 32 (CO=16)
    constexpr int NPAR = CO / 16;       // 2 or 1
    __shared__ float hL[128 * 36];      // stride 36 floats
    __shared__ int sL[128];
    __shared__ int dL[128];

    int tid = threadIdx.x;
    int e0 = blockIdx.x * 128;
    if (tid < 128) sL[tid] = ei[e0 + tid];
    else           dL[tid - 128] = ei[EE + e0 + (tid - 128)];
    __syncthreads();
    for (int idx = tid; idx < 1024; idx += 256) {
        int row = idx >> 3, c = idx & 7;
        const float4* hr = (const float4*)(hin + (size_t)sL[row] * 32);
        *(float4*)&hL[row * 36 + c * 4] = hr[c];
    }
    __syncthreads();

    int wave = tid >> 6, lane = tid & 63, quad = lane >> 4, col = lane & 15;

    uint4 a[2][3];
    int et0 = blockIdx.x * 8 + wave * 2;
#pragma unroll
    for (int st = 0; st < 2; ++st)
#pragma unroll
        for (int s = 0; s < 3; ++s)
            a[st][s] = Pf[((size_t)(et0 + st) * 3 + s) * 64 + lane];

    float msg[2][NPAR][4];
#pragma unroll
    for (int st = 0; st < 2; ++st)
#pragma unroll
        for (int p = 0; p < NPAR; ++p)
#pragma unroll
            for (int r = 0; r < 4; ++r) msg[st][p][r] = 0.f;

#pragma unroll 2
    for (int jt = 0; jt < JT; ++jt) {
        uint4 b0 = Wf[((size_t)jt * 3 + 0) * 64 + lane];
        uint4 b1 = Wf[((size_t)jt * 3 + 1) * 64 + lane];
        uint4 b2 = Wf[((size_t)jt * 3 + 2) * 64 + lane];
        int i   = (CO == 32) ? (jt >> 1) : jt;
        int par = (CO == 32) ? (jt & 1) : 0;
#pragma unroll
        for (int st = 0; st < 2; ++st) {
            f32x4 c = {0.f, 0.f, 0.f, 0.f};
            c = __builtin_amdgcn_mfma_f32_16x16x32_bf16(bc8(a[st][0]), bc8(b0), c, 0, 0, 0);
            c = __builtin_amdgcn_mfma_f32_16x16x32_bf16(bc8(a[st][1]), bc8(b1), c, 0, 0, 0);
            c = __builtin_amdgcn_mfma_f32_16x16x32_bf16(bc8(a[st][2]), bc8(b2), c, 0, 0, 0);
#pragma unroll
            for (int r = 0; r < 4; ++r) {
                float hv = hL[(wave * 32 + st * 16 + quad * 4 + r) * 36 + i];
                msg[st][par][r] += hv * fmaxf(c[r], 0.f);
            }
        }
    }

#pragma unroll
    for (int st = 0; st < 2; ++st)
#pragma unroll
        for (int r = 0; r < 4; ++r) {
            int dv = dL[wave * 32 + st * 16 + quad * 4 + r];
#pragma unroll
            for (int p = 0; p < NPAR; ++p)
                atomicAdd(&aggr[(size_t)dv * CO + p * 16 + col], msg[st][p][r]);
        }
}

// ---------------------------------------------------------------------------
// node update: h' = relu(aggr/cnt + h @ root + bias)
// ---------------------------------------------------------------------------
template<int CO>
__global__ __launch_bounds__(256)
void k_update(const float* __restrict__ aggr, const float* __restrict__ cntInv,
              const float* __restrict__ hin, const float* __restrict__ root,
              const float* __restrict__ bias, float* __restrict__ hout)
{
    __shared__ float rL[32 * CO];
    __shared__ float bL[CO];
    int tid = threadIdx.x;
    for (int idx = tid; idx < 32 * CO; idx += 256) rL[idx] = root[idx];
    if (tid < CO) bL[tid] = bias[tid];
    __syncthreads();
    int gid = blockIdx.x * 256 + tid;
    int v = gid / CO;
    int o = gid % CO;
    float acc = aggr[gid] * cntInv[v] + bL[o];
    const float* hr = hin + (size_t)v * 32;
#pragma unroll
    for (int i = 0; i < 32; ++i) acc += hr[i] * rL[i * CO + o];
    hout[gid] = fmaxf(acc, 0.f);
}

// ---------------------------------------------------------------------------
extern "C" void kernel_launch(void* const* d_in, const int* in_sizes, int n_in,
                              void* d_out, int out_size, void* d_ws, size_t ws_size,
                              hipStream_t stream)
{
    const float* x          = (const float*)d_in[0];
    const float* pos        = (const float*)d_in[1];
    const float* x_skip     = (const float*)d_in[3];
    const float* pos_skip   = (const float*)d_in[4];
    const int*   batch_skip = (const int*)  d_in[5];
    const int*   ei         = (const int*)  d_in[6];
    const float* gt         = (const float*)d_in[7];
    const float* Wq_w       = (const float*)d_in[8];
    const float* Wq_b       = (const float*)d_in[9];
    const float* Wk_w       = (const float*)d_in[10];
    const float* Wk_b       = (const float*)d_in[11];
    const float* Wv_w       = (const float*)d_in[12];
    const float* Wv_b       = (const float*)d_in[13];
    const float* in_proj_w  = (const float*)d_in[14];
    const float* in_proj_b  = (const float*)d_in[15];
    const float* out_w      = (const float*)d_in[16];
    const float* out_b      = (const float*)d_in[17];
    const float* nn_w0 = (const float*)d_in[18]; const float* nn_b0 = (const float*)d_in[19];
    const float* root0 = (const float*)d_in[20]; const float* bias0 = (const float*)d_in[21];
    const float* nn_w1 = (const float*)d_in[22]; const float* nn_b1 = (const float*)d_in[23];
    const float* root1 = (const float*)d_in[24]; const float* bias1 = (const float*)d_in[25];
    const float* nn_w2 = (const float*)d_in[26]; const float* nn_b2 = (const float*)d_in[27];
    const float* root2 = (const float*)d_in[28]; const float* bias2 = (const float*)d_in[29];

    char* wsb = (char*)d_ws;
    size_t off = 0;
    auto carve = [&](size_t bytes) { char* p = wsb + off; off += (bytes + 255) & ~(size_t)255; return p; };
    float* hA   = (float*)carve((size_t)MM * 32 * 4);
    float* hB   = (float*)carve((size_t)MM * 32 * 4);
    float* aggr = (float*)carve((size_t)MM * 32 * 4);
    unsigned short* Pf  = (unsigned short*)carve((size_t)EE * 96 * 2);
    unsigned short* Wf0 = (unsigned short*)carve((size_t)1024 * 96 * 2);
    unsigned short* Wf1 = (unsigned short*)carve((size_t)1024 * 96 * 2);
    unsigned short* Wf2 = (unsigned short*)carve((size_t)512 * 96 * 2);
    float* cnt  = (float*)carve((size_t)MM * 4);
    float* kall = (float*)carve((size_t)NB * 16 * 64 * 4);
    float* V2   = (float*)carve((size_t)NB * 16 * 4 * 64 * 4);
    float* qW   = (float*)carve(192 * 4);
    float* qb2  = (float*)carve(64 * 4);
    float* KtVt = (float*)carve((size_t)NB * 2 * 16 * 64 * 4);

    float* h_final   = (float*)d_out;                 // [M,16]
    float* out_pos   = (float*)d_out + (size_t)MM * 16;
    float* out_batch = (float*)d_out + (size_t)MM * 19;

    hipMemsetAsync(cnt, 0, (size_t)MM * sizeof(float), stream);

    k_tokens1<<<64, 128, 0, stream>>>(gt, Wk_w, Wk_b, Wv_w, Wv_b, KtVt);
    k_tokens2<<<NB, 256, 0, stream>>>(KtVt, in_proj_w, in_proj_b, out_w, Wq_w, Wq_b,
                                      kall, V2, qW, qb2);
    k_knn<<<MM / 256, 256, 0, stream>>>(pos, pos_skip, x, x_skip, batch_skip,
                                        hA, out_pos, out_batch);
    k_edge_attn<<<EE / 256, 256, 0, stream>>>(pos_skip, ei, kall, V2, qW, qb2, out_b, Pf);
    k_count<<<EE / 256, 256, 0, stream>>>(ei, cnt);
    k_inv<<<MM / 256, 256, 0, stream>>>(cnt);
    k_repackW<<<(1024 * 96) / 256, 256, 0, stream>>>(nn_w0, nn_b0, Wf0, 1024 * 96);
    k_repackW<<<(1024 * 96) / 256, 256, 0, stream>>>(nn_w1, nn_b1, Wf1, 1024 * 96);
    k_repackW<<<(512 * 96) / 256, 256, 0, stream>>>(nn_w2, nn_b2, Wf2, 512 * 96);

    // layer 0: hA -> hB
    hipMemsetAsync(aggr, 0, (size_t)MM * 32 * sizeof(float), stream);
    k_conv_mfma<32><<<EE / 128, 256, 0, stream>>>((const uint4*)Pf, hA, ei, (const uint4*)Wf0, aggr);
    k_update<32><<<(MM * 32) / 256, 256, 0, stream>>>(aggr, cnt, hA, root0, bias0, hB);
    // layer 1: hB -> hA
    hipMemsetAsync(aggr, 0, (size_t)MM * 32 * sizeof(float), stream);
    k_conv_mfma<32><<<EE / 128, 256, 0, stream>>>((const uint4*)Pf, hB, ei, (const uint4*)Wf1, aggr);
    k_update<32><<<(MM * 32) / 256, 256, 0, stream>>>(aggr, cnt, hB, root1, bias1, hA);
    // layer 2: hA -> d_out
    hipMemsetAsync(aggr, 0, (size_t)MM * 16 * sizeof(float), stream);
    k_conv_mfma<16><<<EE / 128, 256, 0, stream>>>((const uint4*)Pf, hA, ei, (const uint4*)Wf2, aggr);
    k_update<16><<<(MM * 16) / 256, 256, 0, stream>>>(aggr, cnt, hA, root2, bias2, h_final);
}

// Round 3
// 441.429 us; speedup vs baseline: 3.4546x; 1.3044x over previous
//
#include <hip/hip_runtime.h>
#include <math.h>

#define NB    4        // graphs
#define NN    8192     // coarse nodes
#define MM    65536    // fine nodes
#define EE    131072   // edges
#define NPG   2048     // coarse per graph

typedef short short8 __attribute__((ext_vector_type(8)));
typedef float f32x4  __attribute__((ext_vector_type(4)));

static __device__ inline unsigned short f2b(float f) {
    unsigned u = __float_as_uint(f);
    u += 0x7fffu + ((u >> 16) & 1u);           // RNE
    return (unsigned short)(u >> 16);
}
static __device__ inline unsigned f2b_pack(float a, float b) {
    unsigned x = __float_as_uint(a); x += 0x7fffu + ((x >> 16) & 1u);
    unsigned y = __float_as_uint(b); y += 0x7fffu + ((y >> 16) & 1u);
    return (x >> 16) | (y & 0xffff0000u);
}
static __device__ inline short8 bc8(uint4 v) {
    union { uint4 u; short8 s; } c; c.u = v; return c.s;
}

// ---------------------------------------------------------------------------
// knn_interpolate (k=3): 1024 blocks x 256 thr; block = 64 fine nodes,
// 4 waves each scan a 512-candidate slice with branchless packed-key top-3;
// merge via LDS; exact-distance recompute for weights; 4-thread output fan-out.
// ---------------------------------------------------------------------------
__global__ __launch_bounds__(256)
void k_knn(const float* __restrict__ pos, const float* __restrict__ pos_skip,
           const float* __restrict__ x, const float* __restrict__ x_skip,
           const int* __restrict__ batch_skip,
           float* __restrict__ h0, float* __restrict__ out_pos,
           float* __restrict__ out_batch)
{
    __shared__ float4 cp[NPG];                 // coarse (x,y,z,|p|^2)  32 KB
    __shared__ unsigned pk[4 * 64 * 3];        // partial top-3 keys    3 KB
    __shared__ unsigned mk[64 * 3];            // merged top-3 keys

    int tid = threadIdx.x;
    int g = blockIdx.x >> 8;                   // 256 blocks per graph
    int cbase = g * NPG;
    for (int c = tid; c < NPG; c += 256) {
        float px = pos[(cbase + c) * 3 + 0];
        float py = pos[(cbase + c) * 3 + 1];
        float pz = pos[(cbase + c) * 3 + 2];
        cp[c] = make_float4(px, py, pz, px * px + py * py + pz * pz);
    }
    __syncthreads();

    int lane6 = tid & 63;                      // fine node within block
    int slice = tid >> 6;                      // candidate slice 0..3
    int f = blockIdx.x * 64 + lane6;
    float fx = pos_skip[f * 3 + 0], fy = pos_skip[f * 3 + 1], fz = pos_skip[f * 3 + 2];
    float fq = fx * fx + fy * fy + fz * fz;

    unsigned k0 = 0xFFFFFFFFu, k1 = 0xFFFFFFFFu, k2 = 0xFFFFFFFFu;
    int c0 = slice * 512;
#pragma unroll 4
    for (int c = c0; c < c0 + 512; ++c) {
        float4 cc = cp[c];
        float s = fx * cc.x + fy * cc.y + fz * cc.z;
        float d = fmaxf(fq + cc.w - 2.f * s, 0.f);
        unsigned key = (__float_as_uint(d) & 0xFFFFF800u) | (unsigned)c;
        unsigned b  = max(k0, key); k0 = min(k0, key);
        unsigned c2 = max(k1, b);   k1 = min(k1, b);
        k2 = min(k2, c2);
    }
    pk[(slice * 64 + lane6) * 3 + 0] = k0;
    pk[(slice * 64 + lane6) * 3 + 1] = k1;
    pk[(slice * 64 + lane6) * 3 + 2] = k2;
    __syncthreads();

    if (tid < 64) {
        unsigned m0 = 0xFFFFFFFFu, m1 = 0xFFFFFFFFu, m2 = 0xFFFFFFFFu;
#pragma unroll
        for (int s = 0; s < 4; ++s)
#pragma unroll
            for (int r = 0; r < 3; ++r) {
                unsigned key = pk[(s * 64 + tid) * 3 + r];
                unsigned b  = max(m0, key); m0 = min(m0, key);
                unsigned c2 = max(m1, b);   m1 = min(m1, b);
                m2 = min(m2, c2);
            }
        mk[tid * 3 + 0] = m0; mk[tid * 3 + 1] = m1; mk[tid * 3 + 2] = m2;
        // passthrough outputs (this thread owns fine node f, slice==0)
        out_pos[f * 3 + 0] = fx; out_pos[f * 3 + 1] = fy; out_pos[f * 3 + 2] = fz;
        out_batch[f] = (float)batch_skip[f];
    }
    __syncthreads();

    // output fan-out: 4 threads per fine node
    int fl = tid >> 2, part = tid & 3;
    int f2 = blockIdx.x * 64 + fl;
    float gx = pos_skip[f2 * 3 + 0], gy = pos_skip[f2 * 3 + 1], gz = pos_skip[f2 * 3 + 2];
    float gq = gx * gx + gy * gy + gz * gz;
    float w[3]; int ix[3];
#pragma unroll
    for (int r = 0; r < 3; ++r) {
        int idx = (int)(mk[fl * 3 + r] & 2047u);
        float4 cc = cp[idx];
        float d = fmaxf(gq + cc.w - 2.f * (gx * cc.x + gy * cc.y + gz * cc.z), 0.f);
        w[r] = 1.f / fmaxf(d, 1e-16f);
        ix[r] = idx;
    }
    float inv = 1.f / (w[0] + w[1] + w[2]);
    float w0 = w[0] * inv, w1 = w[1] * inv, w2 = w[2] * inv;
    float4* h04 = (float4*)(h0 + (size_t)f2 * 32);
    if (part < 2) {
        const float4* x4 = (const float4*)x;
        int a0 = (cbase + ix[0]) * 4, a1 = (cbase + ix[1]) * 4, a2 = (cbase + ix[2]) * 4;
#pragma unroll
        for (int j = 0; j < 2; ++j) {
            int cj = part * 2 + j;
            float4 v0 = x4[a0 + cj], v1 = x4[a1 + cj], v2 = x4[a2 + cj];
            float4 r;
            r.x = w0 * v0.x + w1 * v1.x + w2 * v2.x;
            r.y = w0 * v0.y + w1 * v1.y + w2 * v2.y;
            r.z = w0 * v0.z + w1 * v1.z + w2 * v2.z;
            r.w = w0 * v0.w + w1 * v1.w + w2 * v2.w;
            h04[cj] = r;
        }
    } else {
        const float4* xs4 = (const float4*)x_skip;
#pragma unroll
        for (int j = 0; j < 2; ++j) {
            int cj = (part - 2) * 2 + j;
            h04[4 + cj] = xs4[f2 * 4 + cj];
        }
    }
}

// ---------------------------------------------------------------------------
// token prep 1: Kt/Vt = gt @ W^T + b + pe   -> KtVt [B][2][16][64]
// ---------------------------------------------------------------------------
__global__ __launch_bounds__(128)
void k_tokens1(const float* __restrict__ gt,
               const float* __restrict__ Wk_w, const float* __restrict__ Wk_b,
               const float* __restrict__ Wv_w, const float* __restrict__ Wv_b,
               float* __restrict__ KtVt)
{
    int b = blockIdx.x >> 4;
    int t = blockIdx.x & 15;
    int which = threadIdx.x >> 6;
    int d = threadIdx.x & 63;
    const float* W = which ? Wv_w : Wk_w;
    const float* bias = which ? Wv_b : Wk_b;
    const float4* row = (const float4*)(gt + (size_t)(b * 16 + t) * 1024);
    const float4* wr = (const float4*)(W + (size_t)d * 1024);
    float acc = 0.f;
    for (int c = 0; c < 256; ++c) {
        float4 a = row[c], w = wr[c];
        acc += a.x * w.x; acc += a.y * w.y; acc += a.z * w.z; acc += a.w * w.w;
    }
    int i2 = d >> 1;
    float dv = expf((float)(2 * i2) * (-0.14391156831212787f)); // -ln(10000)/64
    float ang = (float)t * dv;
    float pe = (d & 1) ? cosf(ang) : sinf(ang);
    KtVt[((size_t)(b * 2 + which) * 16 + t) * 64 + d] = acc + bias[d] + pe;
}

// ---------------------------------------------------------------------------
// token prep 2: k heads, V2 = out_w-folded v heads, qW/qb2 fold
// ---------------------------------------------------------------------------
__global__ __launch_bounds__(256)
void k_tokens2(const float* __restrict__ KtVt,
               const float* __restrict__ in_proj_w, const float* __restrict__ in_proj_b,
               const float* __restrict__ out_w,
               const float* __restrict__ Wq_w, const float* __restrict__ Wq_b,
               float* __restrict__ kall, float* __restrict__ V2,
               float* __restrict__ qW, float* __restrict__ qb2)
{
    int b = blockIdx.x;
    __shared__ float KtL[1024], VtL[1024], vv[1024];
    for (int idx = threadIdx.x; idx < 1024; idx += 256) {
        KtL[idx] = KtVt[(size_t)(b * 2 + 0) * 1024 + idx];
        VtL[idx] = KtVt[(size_t)(b * 2 + 1) * 1024 + idx];
    }
    __syncthreads();
    for (int idx = threadIdx.x; idx < 2048; idx += 256) {
        int which = idx >> 10; int td = idx & 1023; int t = td >> 6; int j = td & 63;
        int r = (which ? 128 : 64) + j;
        const float* w = in_proj_w + (size_t)r * 64;
        const float* src = which ? VtL : KtL;
        float acc = in_proj_b[r];
#pragma unroll 8
        for (int dd = 0; dd < 64; ++dd) acc += src[t * 64 + dd] * w[dd];
        if (which) vv[t * 64 + j] = acc;
        else kall[(size_t)(b * 16 + t) * 64 + j] = acc;
    }
    __syncthreads();
    for (int idx = threadIdx.x; idx < 4096; idx += 256) {
        int jo = idx & 63; int th = idx >> 6; int h = th & 3; int t = th >> 2;
        float acc = 0.f;
#pragma unroll
        for (int dd = 0; dd < 16; ++dd)
            acc += vv[t * 64 + h * 16 + dd] * out_w[(size_t)jo * 64 + h * 16 + dd];
        V2[(((size_t)(b * 16 + t)) * 4 + h) * 64 + jo] = acc;
    }
    if (b == 0) {
        for (int idx = threadIdx.x; idx < 192; idx += 256) {
            int c = idx >> 6; int j = idx & 63;
            float acc = 0.f;
            for (int dd = 0; dd < 64; ++dd) acc += in_proj_w[(size_t)j * 64 + dd] * Wq_w[dd * 3 + c];
            qW[c * 64 + j] = acc;
        }
        for (int j = threadIdx.x; j < 64; j += 256) {
            float acc = in_proj_b[j];
            for (int dd = 0; dd < 64; ++dd) acc += in_proj_w[(size_t)j * 64 + dd] * Wq_b[dd];
            qb2[j] = acc;
        }
    }
}

// ---------------------------------------------------------------------------
// per-edge cross attention -> Pf in bf16 A-fragment order, K padded to 96:
//   k 0..63  = attn out, k 64..66 = (px,py,pz), k 67 = 1.0 (bias), 68..95 = 0
// ---------------------------------------------------------------------------
__global__ __launch_bounds__(256)
void k_edge_attn(const float* __restrict__ ps, const int* __restrict__ ei,
                 const float* __restrict__ kall, const float* __restrict__ V2g,
                 const float* __restrict__ qW, const float* __restrict__ qb2,
                 const float* __restrict__ ob,
                 unsigned short* __restrict__ Pf)
{
    __shared__ __align__(16) float kk[1024];
    __shared__ __align__(16) float v2s[4096];
    __shared__ float qWs[192];
    __shared__ float qbs[64];
    __shared__ __align__(16) float obs[64];
    int g = blockIdx.x >> 7;
    for (int idx = threadIdx.x; idx < 1024; idx += 256) kk[idx] = kall[(size_t)g * 1024 + idx];
    for (int idx = threadIdx.x; idx < 4096; idx += 256) v2s[idx] = V2g[(size_t)g * 4096 + idx];
    if (threadIdx.x < 192) qWs[threadIdx.x] = qW[threadIdx.x];
    if (threadIdx.x < 64) { qbs[threadIdx.x] = qb2[threadIdx.x]; obs[threadIdx.x] = ob[threadIdx.x]; }
    __syncthreads();

    int e = blockIdx.x * 256 + threadIdx.x;
    int s = ei[e], d = ei[EE + e];
    float sx = ps[s * 3], sy = ps[s * 3 + 1], sz = ps[s * 3 + 2];
    float dx = ps[d * 3], dy = ps[d * 3 + 1], dz = ps[d * 3 + 2];
    float px = dx - sx, py = dy - sy, pz = dz - sz;
    float ex = 0.5f * (dx + sx), ey = 0.5f * (dy + sy), ez = 0.5f * (dz + sz);

    float att[4][16];
    const float4* kk4 = (const float4*)kk;
#pragma unroll
    for (int h = 0; h < 4; ++h) {
        float qh[16];
#pragma unroll
        for (int dd = 0; dd < 16; ++dd) {
            int j = h * 16 + dd;
            qh[dd] = qbs[j] + ex * qWs[j] + ey * qWs[64 + j] + ez * qWs[128 + j];
        }
        float sc[16]; float mx = -3.4e38f;
#pragma unroll
        for (int t = 0; t < 16; ++t) {
            float a = 0.f;
#pragma unroll
            for (int qd = 0; qd < 4; ++qd) {
                float4 kv = kk4[t * 16 + h * 4 + qd];
                a += qh[qd * 4 + 0] * kv.x; a += qh[qd * 4 + 1] * kv.y;
                a += qh[qd * 4 + 2] * kv.z; a += qh[qd * 4 + 3] * kv.w;
            }
            a *= 0.25f;
            sc[t] = a; mx = fmaxf(mx, a);
        }
        float ssum = 0.f;
#pragma unroll
        for (int t = 0; t < 16; ++t) { float eo = expf(sc[t] - mx); sc[t] = eo; ssum += eo; }
        float inv = 1.f / ssum;
#pragma unroll
        for (int t = 0; t < 16; ++t) att[h][t] = sc[t] * inv;
    }

    int et = e >> 4, eL = e & 15;
    const float4* v24 = (const float4*)v2s;
#pragma unroll
    for (int q = 0; q < 16; ++q) {
        float4 acc = ((const float4*)obs)[q];
#pragma unroll
        for (int t = 0; t < 16; ++t)
#pragma unroll
            for (int h = 0; h < 4; ++h) {
                float a = att[h][t];
                float4 vq = v24[(t * 4 + h) * 16 + q];
                acc.x += a * vq.x; acc.y += a * vq.y; acc.z += a * vq.z; acc.w += a * vq.w;
            }
        int k0 = q * 4;
        int st = k0 >> 5, quad = (k0 >> 3) & 3, jj = k0 & 7;
        size_t base = ((size_t)(et * 3 + st) * 64 + quad * 16 + eL) * 8 + jj;
        uint2 v; v.x = f2b_pack(acc.x, acc.y); v.y = f2b_pack(acc.z, acc.w);
        *(uint2*)(Pf + base) = v;
    }
    // tail: step 2 (k = 64..95)
    size_t tb = ((size_t)(et * 3 + 2) * 64 + 0 * 16 + eL) * 8;
    uint2 t0; t0.x = f2b_pack(px, py); t0.y = f2b_pack(pz, 1.0f);
    *(uint2*)(Pf + tb) = t0;
    uint2 z2; z2.x = 0u; z2.y = 0u;
    *(uint2*)(Pf + tb + 4) = z2;
#pragma unroll
    for (int quad = 1; quad < 4; ++quad) {
        size_t zb = ((size_t)(et * 3 + 2) * 64 + quad * 16 + eL) * 8;
        uint4 z4; z4.x = 0u; z4.y = 0u; z4.z = 0u; z4.w = 0u;
        *(uint4*)(Pf + zb) = z4;
    }
}

// ---------------------------------------------------------------------------
// degree count / reciprocal
// ---------------------------------------------------------------------------
__global__ __launch_bounds__(256)
void k_count(const int* __restrict__ ei, float* __restrict__ cnt)
{
    int e = blockIdx.x * 256 + threadIdx.x;
    atomicAdd(&cnt[ei[EE + e]], 1.f);
}

__global__ __launch_bounds__(256)
void k_inv(float* __restrict__ cnt)
{
    int v = blockIdx.x * 256 + threadIdx.x;
    cnt[v] = 1.f / fmaxf(cnt[v], 1.f);
}

// ---------------------------------------------------------------------------
// repack nn_w [rows][67] + nn_b -> bf16 B-fragment stream Wf
// ---------------------------------------------------------------------------
__global__ __launch_bounds__(256)
void k_repackW(const float* __restrict__ nw, const float* __restrict__ nb,
               unsigned short* __restrict__ Wf, int total)
{
    int idx = blockIdx.x * 256 + threadIdx.x;
    if (idx >= total) return;
    int jj = idx & 7;
    int lane = (idx >> 3) & 63;
    int rest = idx >> 9;
    int s = rest % 3;
    int jt = rest / 3;
    int j = jt * 16 + (lane & 15);
    int k = s * 32 + (lane >> 4) * 8 + jj;
    float v;
    if (k < 64)       v = nw[(size_t)j * 67 + 3 + k];
    else if (k < 67)  v = nw[(size_t)j * 67 + (k - 64)];
    else if (k == 67) v = nb[j];
    else              v = 0.f;
    Wf[idx] = f2b(v);
}

// ---------------------------------------------------------------------------
// MFMA edge pass: per wave 32 edges (2 A-frag sets), loop 2*CO j-tiles:
//   we_tile = relu(P @ W^T) via 3x mfma_16x16x32_bf16; msg += h[src][i]*we;
// scatter atomicAdd at the end. No __syncthreads in the j-loop.
// ---------------------------------------------------------------------------
template<int CO>
__global__ __launch_bounds__(256, 4)
void k_conv_mfma(const uint4* __restrict__ Pf, const float* __restrict__ hin,
                 const int* __restrict__ ei, const uint4* __restrict__ Wf,
                 float* __restrict__ aggr)
{
    constexpr int JT = 2 * CO;          // 64 (CO=32) or 32 (CO=16)
    constexpr int NPAR = CO / 16;       // 2 or 1
    __shared__ float hL[128 * 36];      // stride 36 floats
    __shared__ int sL[128];
    __shared__ int dL[128];

    int tid = threadIdx.x;
    int e0 = blockIdx.x * 128;
    if (tid < 128) sL[tid] = ei[e0 + tid];
    else           dL[tid - 128] = ei[EE + e0 + (tid - 128)];
    __syncthreads();
    for (int idx = tid; idx < 1024; idx += 256) {
        int row = idx >> 3, c = idx & 7;
        const float4* hr = (const float4*)(hin + (size_t)sL[row] * 32);
        *(float4*)&hL[row * 36 + c * 4] = hr[c];
    }
    __syncthreads();

    int wave = tid >> 6, lane = tid & 63, quad = lane >> 4, col = lane & 15;

    uint4 a[2][3];
    int et0 = blockIdx.x * 8 + wave * 2;
#pragma unroll
    for (int st = 0; st < 2; ++st)
#pragma unroll
        for (int s = 0; s < 3; ++s)
            a[st][s] = Pf[((size_t)(et0 + st) * 3 + s) * 64 + lane];

    float msg[2][NPAR][4];
#pragma unroll
    for (int st = 0; st < 2; ++st)
#pragma unroll
        for (int p = 0; p < NPAR; ++p)
#pragma unroll
            for (int r = 0; r < 4; ++r) msg[st][p][r] = 0.f;

#pragma unroll 2
    for (int jt = 0; jt < JT; ++jt) {
        uint4 b0 = Wf[((size_t)jt * 3 + 0) * 64 + lane];
        uint4 b1 = Wf[((size_t)jt * 3 + 1) * 64 + lane];
        uint4 b2 = Wf[((size_t)jt * 3 + 2) * 64 + lane];
        int i   = (CO == 32) ? (jt >> 1) : jt;
        int par = (CO == 32) ? (jt & 1) : 0;
#pragma unroll
        for (int st = 0; st < 2; ++st) {
            f32x4 c = {0.f, 0.f, 0.f, 0.f};
            c = __builtin_amdgcn_mfma_f32_16x16x32_bf16(bc8(a[st][0]), bc8(b0), c, 0, 0, 0);
            c = __builtin_amdgcn_mfma_f32_16x16x32_bf16(bc8(a[st][1]), bc8(b1), c, 0, 0, 0);
            c = __builtin_amdgcn_mfma_f32_16x16x32_bf16(bc8(a[st][2]), bc8(b2), c, 0, 0, 0);
#pragma unroll
            for (int r = 0; r < 4; ++r) {
                float hv = hL[(wave * 32 + st * 16 + quad * 4 + r) * 36 + i];
                msg[st][par][r] += hv * fmaxf(c[r], 0.f);
            }
        }
    }

#pragma unroll
    for (int st = 0; st < 2; ++st)
#pragma unroll
        for (int r = 0; r < 4; ++r) {
            int dv = dL[wave * 32 + st * 16 + quad * 4 + r];
#pragma unroll
            for (int p = 0; p < NPAR; ++p)
                atomicAdd(&aggr[(size_t)dv * CO + p * 16 + col], msg[st][p][r]);
        }
}

// ---------------------------------------------------------------------------
// node update: h' = relu(aggr/cnt + h @ root + bias)
// ---------------------------------------------------------------------------
template<int CO>
__global__ __launch_bounds__(256)
void k_update(const float* __restrict__ aggr, const float* __restrict__ cntInv,
              const float* __restrict__ hin, const float* __restrict__ root,
              const float* __restrict__ bias, float* __restrict__ hout)
{
    __shared__ float rL[32 * CO];
    __shared__ float bL[CO];
    int tid = threadIdx.x;
    for (int idx = tid; idx < 32 * CO; idx += 256) rL[idx] = root[idx];
    if (tid < CO) bL[tid] = bias[tid];
    __syncthreads();
    int gid = blockIdx.x * 256 + tid;
    int v = gid / CO;
    int o = gid % CO;
    float acc = aggr[gid] * cntInv[v] + bL[o];
    const float* hr = hin + (size_t)v * 32;
#pragma unroll
    for (int i = 0; i < 32; ++i) acc += hr[i] * rL[i * CO + o];
    hout[gid] = fmaxf(acc, 0.f);
}

// ---------------------------------------------------------------------------
extern "C" void kernel_launch(void* const* d_in, const int* in_sizes, int n_in,
                              void* d_out, int out_size, void* d_ws, size_t ws_size,
                              hipStream_t stream)
{
    const float* x          = (const float*)d_in[0];
    const float* pos        = (const float*)d_in[1];
    const float* x_skip     = (const float*)d_in[3];
    const float* pos_skip   = (const float*)d_in[4];
    const int*   batch_skip = (const int*)  d_in[5];
    const int*   ei         = (const int*)  d_in[6];
    const float* gt         = (const float*)d_in[7];
    const float* Wq_w       = (const float*)d_in[8];
    const float* Wq_b       = (const float*)d_in[9];
    const float* Wk_w       = (const float*)d_in[10];
    const float* Wk_b       = (const float*)d_in[11];
    const float* Wv_w       = (const float*)d_in[12];
    const float* Wv_b       = (const float*)d_in[13];
    const float* in_proj_w  = (const float*)d_in[14];
    const float* in_proj_b  = (const float*)d_in[15];
    const float* out_w      = (const float*)d_in[16];
    const float* out_b      = (const float*)d_in[17];
    const float* nn_w0 = (const float*)d_in[18]; const float* nn_b0 = (const float*)d_in[19];
    const float* root0 = (const float*)d_in[20]; const float* bias0 = (const float*)d_in[21];
    const float* nn_w1 = (const float*)d_in[22]; const float* nn_b1 = (const float*)d_in[23];
    const float* root1 = (const float*)d_in[24]; const float* bias1 = (const float*)d_in[25];
    const float* nn_w2 = (const float*)d_in[26]; const float* nn_b2 = (const float*)d_in[27];
    const float* root2 = (const float*)d_in[28]; const float* bias2 = (const float*)d_in[29];

    char* wsb = (char*)d_ws;
    size_t off = 0;
    auto carve = [&](size_t bytes) { char* p = wsb + off; off += (bytes + 255) & ~(size_t)255; return p; };
    float* hA   = (float*)carve((size_t)MM * 32 * 4);
    float* hB   = (float*)carve((size_t)MM * 32 * 4);
    float* aggr = (float*)carve((size_t)MM * 32 * 4);
    unsigned short* Pf  = (unsigned short*)carve((size_t)EE * 96 * 2);
    unsigned short* Wf0 = (unsigned short*)carve((size_t)1024 * 96 * 2);
    unsigned short* Wf1 = (unsigned short*)carve((size_t)1024 * 96 * 2);
    unsigned short* Wf2 = (unsigned short*)carve((size_t)512 * 96 * 2);
    float* cnt  = (float*)carve((size_t)MM * 4);
    float* kall = (float*)carve((size_t)NB * 16 * 64 * 4);
    float* V2   = (float*)carve((size_t)NB * 16 * 4 * 64 * 4);
    float* qW   = (float*)carve(192 * 4);
    float* qb2  = (float*)carve(64 * 4);
    float* KtVt = (float*)carve((size_t)NB * 2 * 16 * 64 * 4);

    float* h_final   = (float*)d_out;                 // [M,16]
    float* out_pos   = (float*)d_out + (size_t)MM * 16;
    float* out_batch = (float*)d_out + (size_t)MM * 19;

    hipMemsetAsync(cnt, 0, (size_t)MM * sizeof(float), stream);

    k_tokens1<<<64, 128, 0, stream>>>(gt, Wk_w, Wk_b, Wv_w, Wv_b, KtVt);
    k_tokens2<<<NB, 256, 0, stream>>>(KtVt, in_proj_w, in_proj_b, out_w, Wq_w, Wq_b,
                                      kall, V2, qW, qb2);
    k_knn<<<MM / 64, 256, 0, stream>>>(pos, pos_skip, x, x_skip, batch_skip,
                                       hA, out_pos, out_batch);
    k_edge_attn<<<EE / 256, 256, 0, stream>>>(pos_skip, ei, kall, V2, qW, qb2, out_b, Pf);
    k_count<<<EE / 256, 256, 0, stream>>>(ei, cnt);
    k_inv<<<MM / 256, 256, 0, stream>>>(cnt);
    k_repackW<<<(1024 * 96) / 256, 256, 0, stream>>>(nn_w0, nn_b0, Wf0, 1024 * 96);
    k_repackW<<<(1024 * 96) / 256, 256, 0, stream>>>(nn_w1, nn_b1, Wf1, 1024 * 96);
    k_repackW<<<(512 * 96) / 256, 256, 0, stream>>>(nn_w2, nn_b2, Wf2, 512 * 96);

    // layer 0: hA -> hB
    hipMemsetAsync(aggr, 0, (size_t)MM * 32 * sizeof(float), stream);
    k_conv_mfma<32><<<EE / 128, 256, 0, stream>>>((const uint4*)Pf, hA, ei, (const uint4*)Wf0, aggr);
    k_update<32><<<(MM * 32) / 256, 256, 0, stream>>>(aggr, cnt, hA, root0, bias0, hB);
    // layer 1: hB -> hA
    hipMemsetAsync(aggr, 0, (size_t)MM * 32 * sizeof(float), stream);
    k_conv_mfma<32><<<EE / 128, 256, 0, stream>>>((const uint4*)Pf, hB, ei, (const uint4*)Wf1, aggr);
    k_update<32><<<(MM * 32) / 256, 256, 0, stream>>>(aggr, cnt, hB, root1, bias1, hA);
    // layer 2: hA -> d_out
    hipMemsetAsync(aggr, 0, (size_t)MM * 16 * sizeof(float), stream);
    k_conv_mfma<16><<<EE / 128, 256, 0, stream>>>((const uint4*)Pf, hA, ei, (const uint4*)Wf2, aggr);
    k_update<16><<<(MM * 16) / 256, 256, 0, stream>>>(aggr, cnt, hA, root2, bias2, h_final);
}

// Round 4
// 425.654 us; speedup vs baseline: 3.5826x; 1.0371x over previous
//
#include <hip/hip_runtime.h>
#include <math.h>

#define NB    4        // graphs
#define NN    8192     // coarse nodes
#define MM    65536    // fine nodes
#define EE    131072   // edges
#define NPG   2048     // coarse per graph

typedef short short8 __attribute__((ext_vector_type(8)));
typedef float f32x4  __attribute__((ext_vector_type(4)));

static __device__ inline unsigned short f2b(float f) {
    unsigned u = __float_as_uint(f);
    u += 0x7fffu + ((u >> 16) & 1u);           // RNE
    return (unsigned short)(u >> 16);
}
static __device__ inline unsigned f2b_pack(float a, float b) {
    unsigned x = __float_as_uint(a); x += 0x7fffu + ((x >> 16) & 1u);
    unsigned y = __float_as_uint(b); y += 0x7fffu + ((y >> 16) & 1u);
    return (x >> 16) | (y & 0xffff0000u);
}
static __device__ inline short8 bc8(uint4 v) {
    union { uint4 u; short8 s; } c; c.u = v; return c.s;
}

// ---------------------------------------------------------------------------
// knn_interpolate (k=3): 512 blocks x 256 thr; block = 128 fine nodes.
// Each thread scans a 512-candidate slice for TWO nodes (one LDS broadcast
// read feeds 2 independent chains). Keys: 23 bits of distance + 9-bit local
// idx. Merge recomputes EXACT distances for the 12 survivors (u64 top-3),
// so final selection is exact-formula (restores round-2 accuracy).
// ---------------------------------------------------------------------------
__global__ __launch_bounds__(256)
void k_knn(const float* __restrict__ pos, const float* __restrict__ pos_skip,
           const float* __restrict__ x, const float* __restrict__ x_skip,
           const int* __restrict__ batch_skip,
           float* __restrict__ h0, float* __restrict__ out_pos,
           float* __restrict__ out_batch)
{
    __shared__ float4 cp[NPG];                 // 32 KB coarse (x,y,z,|p|^2)
    __shared__ unsigned pk[4][128][3];         // 6 KB partial top-3 keys
    __shared__ float wFin[128][3];
    __shared__ int   iFin[128][3];

    int tid = threadIdx.x;
    int g = blockIdx.x >> 7;                   // 128 blocks per graph
    int cbase = g * NPG;
    for (int c = tid; c < NPG; c += 256) {
        float px = pos[(cbase + c) * 3 + 0];
        float py = pos[(cbase + c) * 3 + 1];
        float pz = pos[(cbase + c) * 3 + 2];
        cp[c] = make_float4(px, py, pz, px * px + py * py + pz * pz);
    }
    __syncthreads();

    int p = tid & 63;                          // node-pair id
    int slice = tid >> 6;                      // candidate slice 0..3
    int fbase = blockIdx.x * 128;
    int f0 = fbase + p, f1 = fbase + 64 + p;
    float fx0 = pos_skip[f0 * 3 + 0], fy0 = pos_skip[f0 * 3 + 1], fz0 = pos_skip[f0 * 3 + 2];
    float fx1 = pos_skip[f1 * 3 + 0], fy1 = pos_skip[f1 * 3 + 1], fz1 = pos_skip[f1 * 3 + 2];
    float fq0 = fx0 * fx0 + fy0 * fy0 + fz0 * fz0;
    float fq1 = fx1 * fx1 + fy1 * fy1 + fz1 * fz1;

    unsigned ka0 = 0xFFFFFFFFu, ka1 = 0xFFFFFFFFu, ka2 = 0xFFFFFFFFu;
    unsigned kb0 = 0xFFFFFFFFu, kb1 = 0xFFFFFFFFu, kb2 = 0xFFFFFFFFu;
    const float4* cps = cp + slice * 512;
#pragma unroll 8
    for (int l = 0; l < 512; ++l) {
        float4 cc = cps[l];
        float s0 = fx0 * cc.x + fy0 * cc.y + fz0 * cc.z;
        float d0 = fmaxf(fq0 + cc.w - 2.f * s0, 0.f);
        unsigned k = (__float_as_uint(d0) & 0xFFFFFE00u) | (unsigned)l;
        unsigned t1 = max(ka0, k); ka0 = min(ka0, k);
        unsigned t2 = max(ka1, t1); ka1 = min(ka1, t1);
        ka2 = min(ka2, t2);
        float s1 = fx1 * cc.x + fy1 * cc.y + fz1 * cc.z;
        float d1 = fmaxf(fq1 + cc.w - 2.f * s1, 0.f);
        unsigned kq = (__float_as_uint(d1) & 0xFFFFFE00u) | (unsigned)l;
        t1 = max(kb0, kq); kb0 = min(kb0, kq);
        t2 = max(kb1, t1); kb1 = min(kb1, t1);
        kb2 = min(kb2, t2);
    }
    pk[slice][p][0] = ka0; pk[slice][p][1] = ka1; pk[slice][p][2] = ka2;
    pk[slice][64 + p][0] = kb0; pk[slice][64 + p][1] = kb1; pk[slice][64 + p][2] = kb2;
    __syncthreads();

    if (tid < 128) {
        int n = tid;
        int f = fbase + n;
        float gx = pos_skip[f * 3 + 0], gy = pos_skip[f * 3 + 1], gz = pos_skip[f * 3 + 2];
        float gq = gx * gx + gy * gy + gz * gz;
        unsigned long long m0 = ~0ull, m1 = ~0ull, m2 = ~0ull;
#pragma unroll
        for (int s = 0; s < 4; ++s)
#pragma unroll
            for (int r = 0; r < 3; ++r) {
                unsigned key = pk[s][n][r];
                int c = s * 512 + (int)(key & 511u);
                float4 cc = cp[c];
                float d = fmaxf(gq + cc.w - 2.f * (gx * cc.x + gy * cc.y + gz * cc.z), 0.f);
                unsigned long long kk = ((unsigned long long)__float_as_uint(d) << 32) | (unsigned)c;
                unsigned long long t1 = m0 > kk ? m0 : kk; m0 = m0 < kk ? m0 : kk;
                unsigned long long t2 = m1 > t1 ? m1 : t1; m1 = m1 < t1 ? m1 : t1;
                m2 = m2 < t2 ? m2 : t2;
            }
        float d0 = __uint_as_float((unsigned)(m0 >> 32));
        float d1 = __uint_as_float((unsigned)(m1 >> 32));
        float d2 = __uint_as_float((unsigned)(m2 >> 32));
        float w0 = 1.f / fmaxf(d0, 1e-16f);
        float w1 = 1.f / fmaxf(d1, 1e-16f);
        float w2 = 1.f / fmaxf(d2, 1e-16f);
        float inv = 1.f / (w0 + w1 + w2);
        wFin[n][0] = w0 * inv; wFin[n][1] = w1 * inv; wFin[n][2] = w2 * inv;
        iFin[n][0] = cbase + (int)(m0 & 2047u);
        iFin[n][1] = cbase + (int)(m1 & 2047u);
        iFin[n][2] = cbase + (int)(m2 & 2047u);
        out_pos[f * 3 + 0] = gx; out_pos[f * 3 + 1] = gy; out_pos[f * 3 + 2] = gz;
        out_batch[f] = (float)batch_skip[f];
    }
    __syncthreads();

    // output fan-out: 2 threads per fine node
    int n2 = tid >> 1, half = tid & 1;
    int f2 = fbase + n2;
    float4* h04 = (float4*)(h0 + (size_t)f2 * 32);
    if (half == 0) {
        const float4* x4 = (const float4*)x;
        float w0 = wFin[n2][0], w1 = wFin[n2][1], w2 = wFin[n2][2];
        int a0 = iFin[n2][0] * 4, a1 = iFin[n2][1] * 4, a2 = iFin[n2][2] * 4;
#pragma unroll
        for (int j = 0; j < 4; ++j) {
            float4 v0 = x4[a0 + j], v1 = x4[a1 + j], v2 = x4[a2 + j];
            float4 r;
            r.x = w0 * v0.x + w1 * v1.x + w2 * v2.x;
            r.y = w0 * v0.y + w1 * v1.y + w2 * v2.y;
            r.z = w0 * v0.z + w1 * v1.z + w2 * v2.z;
            r.w = w0 * v0.w + w1 * v1.w + w2 * v2.w;
            h04[j] = r;
        }
    } else {
        const float4* xs4 = (const float4*)x_skip;
#pragma unroll
        for (int j = 0; j < 4; ++j) h04[4 + j] = xs4[f2 * 4 + j];
    }
}

// ---------------------------------------------------------------------------
// token prep 1: Kt/Vt = gt @ W^T + b + pe   -> KtVt [B][2][16][64]
// ---------------------------------------------------------------------------
__global__ __launch_bounds__(128)
void k_tokens1(const float* __restrict__ gt,
               const float* __restrict__ Wk_w, const float* __restrict__ Wk_b,
               const float* __restrict__ Wv_w, const float* __restrict__ Wv_b,
               float* __restrict__ KtVt)
{
    int b = blockIdx.x >> 4;
    int t = blockIdx.x & 15;
    int which = threadIdx.x >> 6;
    int d = threadIdx.x & 63;
    const float* W = which ? Wv_w : Wk_w;
    const float* bias = which ? Wv_b : Wk_b;
    const float4* row = (const float4*)(gt + (size_t)(b * 16 + t) * 1024);
    const float4* wr = (const float4*)(W + (size_t)d * 1024);
    float acc = 0.f;
    for (int c = 0; c < 256; ++c) {
        float4 a = row[c], w = wr[c];
        acc += a.x * w.x; acc += a.y * w.y; acc += a.z * w.z; acc += a.w * w.w;
    }
    int i2 = d >> 1;
    float dv = expf((float)(2 * i2) * (-0.14391156831212787f)); // -ln(10000)/64
    float ang = (float)t * dv;
    float pe = (d & 1) ? cosf(ang) : sinf(ang);
    KtVt[((size_t)(b * 2 + which) * 16 + t) * 64 + d] = acc + bias[d] + pe;
}

// ---------------------------------------------------------------------------
// token prep 2: k heads, V2 = out_w-folded v heads, qW/qb2 fold
// ---------------------------------------------------------------------------
__global__ __launch_bounds__(256)
void k_tokens2(const float* __restrict__ KtVt,
               const float* __restrict__ in_proj_w, const float* __restrict__ in_proj_b,
               const float* __restrict__ out_w,
               const float* __restrict__ Wq_w, const float* __restrict__ Wq_b,
               float* __restrict__ kall, float* __restrict__ V2,
               float* __restrict__ qW, float* __restrict__ qb2)
{
    int b = blockIdx.x;
    __shared__ float KtL[1024], VtL[1024], vv[1024];
    for (int idx = threadIdx.x; idx < 1024; idx += 256) {
        KtL[idx] = KtVt[(size_t)(b * 2 + 0) * 1024 + idx];
        VtL[idx] = KtVt[(size_t)(b * 2 + 1) * 1024 + idx];
    }
    __syncthreads();
    for (int idx = threadIdx.x; idx < 2048; idx += 256) {
        int which = idx >> 10; int td = idx & 1023; int t = td >> 6; int j = td & 63;
        int r = (which ? 128 : 64) + j;
        const float* w = in_proj_w + (size_t)r * 64;
        const float* src = which ? VtL : KtL;
        float acc = in_proj_b[r];
#pragma unroll 8
        for (int dd = 0; dd < 64; ++dd) acc += src[t * 64 + dd] * w[dd];
        if (which) vv[t * 64 + j] = acc;
        else kall[(size_t)(b * 16 + t) * 64 + j] = acc;
    }
    __syncthreads();
    for (int idx = threadIdx.x; idx < 4096; idx += 256) {
        int jo = idx & 63; int th = idx >> 6; int h = th & 3; int t = th >> 2;
        float acc = 0.f;
#pragma unroll
        for (int dd = 0; dd < 16; ++dd)
            acc += vv[t * 64 + h * 16 + dd] * out_w[(size_t)jo * 64 + h * 16 + dd];
        V2[(((size_t)(b * 16 + t)) * 4 + h) * 64 + jo] = acc;
    }
    if (b == 0) {
        for (int idx = threadIdx.x; idx < 192; idx += 256) {
            int c = idx >> 6; int j = idx & 63;
            float acc = 0.f;
            for (int dd = 0; dd < 64; ++dd) acc += in_proj_w[(size_t)j * 64 + dd] * Wq_w[dd * 3 + c];
            qW[c * 64 + j] = acc;
        }
        for (int j = threadIdx.x; j < 64; j += 256) {
            float acc = in_proj_b[j];
            for (int dd = 0; dd < 64; ++dd) acc += in_proj_w[(size_t)j * 64 + dd] * Wq_b[dd];
            qb2[j] = acc;
        }
    }
}

// ---------------------------------------------------------------------------
// per-edge cross attention -> Pf in bf16 A-fragment order, K padded to 96.
// Also fuses the dst-degree count (atomicAdd on cnt).
// ---------------------------------------------------------------------------
__global__ __launch_bounds__(256)
void k_edge_attn(const float* __restrict__ ps, const int* __restrict__ ei,
                 const float* __restrict__ kall, const float* __restrict__ V2g,
                 const float* __restrict__ qW, const float* __restrict__ qb2,
                 const float* __restrict__ ob,
                 unsigned short* __restrict__ Pf, float* __restrict__ cnt)
{
    __shared__ __align__(16) float kk[1024];
    __shared__ __align__(16) float v2s[4096];
    __shared__ float qWs[192];
    __shared__ float qbs[64];
    __shared__ __align__(16) float obs[64];
    int g = blockIdx.x >> 7;
    for (int idx = threadIdx.x; idx < 1024; idx += 256) kk[idx] = kall[(size_t)g * 1024 + idx];
    for (int idx = threadIdx.x; idx < 4096; idx += 256) v2s[idx] = V2g[(size_t)g * 4096 + idx];
    if (threadIdx.x < 192) qWs[threadIdx.x] = qW[threadIdx.x];
    if (threadIdx.x < 64) { qbs[threadIdx.x] = qb2[threadIdx.x]; obs[threadIdx.x] = ob[threadIdx.x]; }
    __syncthreads();

    int e = blockIdx.x * 256 + threadIdx.x;
    int s = ei[e], d = ei[EE + e];
    atomicAdd(&cnt[d], 1.f);
    float sx = ps[s * 3], sy = ps[s * 3 + 1], sz = ps[s * 3 + 2];
    float dx = ps[d * 3], dy = ps[d * 3 + 1], dz = ps[d * 3 + 2];
    float px = dx - sx, py = dy - sy, pz = dz - sz;
    float ex = 0.5f * (dx + sx), ey = 0.5f * (dy + sy), ez = 0.5f * (dz + sz);

    float att[4][16];
    const float4* kk4 = (const float4*)kk;
#pragma unroll
    for (int h = 0; h < 4; ++h) {
        float qh[16];
#pragma unroll
        for (int dd = 0; dd < 16; ++dd) {
            int j = h * 16 + dd;
            qh[dd] = qbs[j] + ex * qWs[j] + ey * qWs[64 + j] + ez * qWs[128 + j];
        }
        float sc[16]; float mx = -3.4e38f;
#pragma unroll
        for (int t = 0; t < 16; ++t) {
            float a = 0.f;
#pragma unroll
            for (int qd = 0; qd < 4; ++qd) {
                float4 kv = kk4[t * 16 + h * 4 + qd];
                a += qh[qd * 4 + 0] * kv.x; a += qh[qd * 4 + 1] * kv.y;
                a += qh[qd * 4 + 2] * kv.z; a += qh[qd * 4 + 3] * kv.w;
            }
            a *= 0.25f;
            sc[t] = a; mx = fmaxf(mx, a);
        }
        float ssum = 0.f;
#pragma unroll
        for (int t = 0; t < 16; ++t) { float eo = expf(sc[t] - mx); sc[t] = eo; ssum += eo; }
        float inv = 1.f / ssum;
#pragma unroll
        for (int t = 0; t < 16; ++t) att[h][t] = sc[t] * inv;
    }

    int et = e >> 4, eL = e & 15;
    const float4* v24 = (const float4*)v2s;
#pragma unroll
    for (int q = 0; q < 16; ++q) {
        float4 acc = ((const float4*)obs)[q];
#pragma unroll
        for (int t = 0; t < 16; ++t)
#pragma unroll
            for (int h = 0; h < 4; ++h) {
                float a = att[h][t];
                float4 vq = v24[(t * 4 + h) * 16 + q];
                acc.x += a * vq.x; acc.y += a * vq.y; acc.z += a * vq.z; acc.w += a * vq.w;
            }
        int k0 = q * 4;
        int st = k0 >> 5, quad = (k0 >> 3) & 3, jj = k0 & 7;
        size_t base = ((size_t)(et * 3 + st) * 64 + quad * 16 + eL) * 8 + jj;
        uint2 v; v.x = f2b_pack(acc.x, acc.y); v.y = f2b_pack(acc.z, acc.w);
        *(uint2*)(Pf + base) = v;
    }
    // tail: step 2 (k = 64..95)
    size_t tb = ((size_t)(et * 3 + 2) * 64 + 0 * 16 + eL) * 8;
    uint2 t0; t0.x = f2b_pack(px, py); t0.y = f2b_pack(pz, 1.0f);
    *(uint2*)(Pf + tb) = t0;
    uint2 z2; z2.x = 0u; z2.y = 0u;
    *(uint2*)(Pf + tb + 4) = z2;
#pragma unroll
    for (int quad = 1; quad < 4; ++quad) {
        size_t zb = ((size_t)(et * 3 + 2) * 64 + quad * 16 + eL) * 8;
        uint4 z4; z4.x = 0u; z4.y = 0u; z4.z = 0u; z4.w = 0u;
        *(uint4*)(Pf + zb) = z4;
    }
}

// ---------------------------------------------------------------------------
// fused repack of all 3 layers' nn_w/nn_b -> bf16 B-fragment streams
// ---------------------------------------------------------------------------
static __device__ inline void repack_one(const float* __restrict__ nw,
                                         const float* __restrict__ nb,
                                         unsigned short* __restrict__ Wf, int idx)
{
    int jj = idx & 7;
    int lane = (idx >> 3) & 63;
    int rest = idx >> 9;
    int s = rest % 3;
    int jt = rest / 3;
    int j = jt * 16 + (lane & 15);
    int k = s * 32 + (lane >> 4) * 8 + jj;
    float v;
    if (k < 64)       v = nw[(size_t)j * 67 + 3 + k];
    else if (k < 67)  v = nw[(size_t)j * 67 + (k - 64)];
    else if (k == 67) v = nb[j];
    else              v = 0.f;
    Wf[idx] = f2b(v);
}

__global__ __launch_bounds__(256)
void k_repackAll(const float* __restrict__ nw0, const float* __restrict__ nb0,
                 const float* __restrict__ nw1, const float* __restrict__ nb1,
                 const float* __restrict__ nw2, const float* __restrict__ nb2,
                 unsigned short* __restrict__ Wf0, unsigned short* __restrict__ Wf1,
                 unsigned short* __restrict__ Wf2)
{
    int idx = blockIdx.x * 256 + threadIdx.x;
    if (idx < 98304)        repack_one(nw0, nb0, Wf0, idx);
    else if (idx < 196608)  repack_one(nw1, nb1, Wf1, idx - 98304);
    else                    repack_one(nw2, nb2, Wf2, idx - 196608);
}

// ---------------------------------------------------------------------------
// MFMA edge pass: per wave 32 edges (2 A-frag sets), loop 2*CO j-tiles:
//   we_tile = relu(P @ W^T) via 3x mfma_16x16x32_bf16; msg += h[src][i]*we;
// scatter atomicAdd at the end. No __syncthreads in the j-loop.
// ---------------------------------------------------------------------------
template<int CO>
__global__ __launch_bounds__(256, 4)
void k_conv_mfma(const uint4* __restrict__ Pf, const float* __restrict__ hin,
                 const int* __restrict__ ei, const uint4* __restrict__ Wf,
                 float* __restrict__ aggr)
{
    constexpr int JT = 2 * CO;          // 64 (CO=32) or 32 (CO=16)
    constexpr int NPAR = CO / 16;       // 2 or 1
    __shared__ float hL[128 * 36];      // stride 36 floats
    __shared__ int sL[128];
    __shared__ int dL[128];

    int tid = threadIdx.x;
    int e0 = blockIdx.x * 128;
    if (tid < 128) sL[tid] = ei[e0 + tid];
    else           dL[tid - 128] = ei[EE + e0 + (tid - 128)];
    __syncthreads();
    for (int idx = tid; idx < 1024; idx += 256) {
        int row = idx >> 3, c = idx & 7;
        const float4* hr = (const float4*)(hin + (size_t)sL[row] * 32);
        *(float4*)&hL[row * 36 + c * 4] = hr[c];
    }
    __syncthreads();

    int wave = tid >> 6, lane = tid & 63, quad = lane >> 4, col = lane & 15;

    uint4 a[2][3];
    int et0 = blockIdx.x * 8 + wave * 2;
#pragma unroll
    for (int st = 0; st < 2; ++st)
#pragma unroll
        for (int s = 0; s < 3; ++s)
            a[st][s] = Pf[((size_t)(et0 + st) * 3 + s) * 64 + lane];

    float msg[2][NPAR][4];
#pragma unroll
    for (int st = 0; st < 2; ++st)
#pragma unroll
        for (int p = 0; p < NPAR; ++p)
#pragma unroll
            for (int r = 0; r < 4; ++r) msg[st][p][r] = 0.f;

#pragma unroll 2
    for (int jt = 0; jt < JT; ++jt) {
        uint4 b0 = Wf[((size_t)jt * 3 + 0) * 64 + lane];
        uint4 b1 = Wf[((size_t)jt * 3 + 1) * 64 + lane];
        uint4 b2 = Wf[((size_t)jt * 3 + 2) * 64 + lane];
        int i   = (CO == 32) ? (jt >> 1) : jt;
        int par = (CO == 32) ? (jt & 1) : 0;
#pragma unroll
        for (int st = 0; st < 2; ++st) {
            f32x4 c = {0.f, 0.f, 0.f, 0.f};
            c = __builtin_amdgcn_mfma_f32_16x16x32_bf16(bc8(a[st][0]), bc8(b0), c, 0, 0, 0);
            c = __builtin_amdgcn_mfma_f32_16x16x32_bf16(bc8(a[st][1]), bc8(b1), c, 0, 0, 0);
            c = __builtin_amdgcn_mfma_f32_16x16x32_bf16(bc8(a[st][2]), bc8(b2), c, 0, 0, 0);
#pragma unroll
            for (int r = 0; r < 4; ++r) {
                float hv = hL[(wave * 32 + st * 16 + quad * 4 + r) * 36 + i];
                msg[st][par][r] += hv * fmaxf(c[r], 0.f);
            }
        }
    }

#pragma unroll
    for (int st = 0; st < 2; ++st)
#pragma unroll
        for (int r = 0; r < 4; ++r) {
            int dv = dL[wave * 32 + st * 16 + quad * 4 + r];
#pragma unroll
            for (int p = 0; p < NPAR; ++p)
                atomicAdd(&aggr[(size_t)dv * CO + p * 16 + col], msg[st][p][r]);
        }
}

// ---------------------------------------------------------------------------
// node update: h' = relu(aggr/cnt + h @ root + bias); zeroes aggr for the
// next layer's atomic pass (replaces per-layer memsets).
// ---------------------------------------------------------------------------
template<int CO>
__global__ __launch_bounds__(256)
void k_update(float* __restrict__ aggr, const float* __restrict__ cnt,
              const float* __restrict__ hin, const float* __restrict__ root,
              const float* __restrict__ bias, float* __restrict__ hout)
{
    __shared__ float rL[32 * CO];
    __shared__ float bL[CO];
    int tid = threadIdx.x;
    for (int idx = tid; idx < 32 * CO; idx += 256) rL[idx] = root[idx];
    if (tid < CO) bL[tid] = bias[tid];
    __syncthreads();
    int gid = blockIdx.x * 256 + tid;
    int v = gid / CO;
    int o = gid % CO;
    float acc = aggr[gid] / fmaxf(cnt[v], 1.f) + bL[o];
    aggr[gid] = 0.f;                    // prep next layer's scatter
    const float* hr = hin + (size_t)v * 32;
#pragma unroll
    for (int i = 0; i < 32; ++i) acc += hr[i] * rL[i * CO + o];
    hout[gid] = fmaxf(acc, 0.f);
}

// ---------------------------------------------------------------------------
extern "C" void kernel_launch(void* const* d_in, const int* in_sizes, int n_in,
                              void* d_out, int out_size, void* d_ws, size_t ws_size,
                              hipStream_t stream)
{
    const float* x          = (const float*)d_in[0];
    const float* pos        = (const float*)d_in[1];
    const float* x_skip     = (const float*)d_in[3];
    const float* pos_skip   = (const float*)d_in[4];
    const int*   batch_skip = (const int*)  d_in[5];
    const int*   ei         = (const int*)  d_in[6];
    const float* gt         = (const float*)d_in[7];
    const float* Wq_w       = (const float*)d_in[8];
    const float* Wq_b       = (const float*)d_in[9];
    const float* Wk_w       = (const float*)d_in[10];
    const float* Wk_b       = (const float*)d_in[11];
    const float* Wv_w       = (const float*)d_in[12];
    const float* Wv_b       = (const float*)d_in[13];
    const float* in_proj_w  = (const float*)d_in[14];
    const float* in_proj_b  = (const float*)d_in[15];
    const float* out_w      = (const float*)d_in[16];
    const float* out_b      = (const float*)d_in[17];
    const float* nn_w0 = (const float*)d_in[18]; const float* nn_b0 = (const float*)d_in[19];
    const float* root0 = (const float*)d_in[20]; const float* bias0 = (const float*)d_in[21];
    const float* nn_w1 = (const float*)d_in[22]; const float* nn_b1 = (const float*)d_in[23];
    const float* root1 = (const float*)d_in[24]; const float* bias1 = (const float*)d_in[25];
    const float* nn_w2 = (const float*)d_in[26]; const float* nn_b2 = (const float*)d_in[27];
    const float* root2 = (const float*)d_in[28]; const float* bias2 = (const float*)d_in[29];

    char* wsb = (char*)d_ws;
    size_t off = 0;
    auto carve = [&](size_t bytes) { char* p = wsb + off; off += (bytes + 255) & ~(size_t)255; return p; };
    float* aggr = (float*)carve((size_t)MM * 32 * 4);   // aggr then cnt: one memset
    float* cnt  = (float*)carve((size_t)MM * 4);
    float* hA   = (float*)carve((size_t)MM * 32 * 4);
    float* hB   = (float*)carve((size_t)MM * 32 * 4);
    unsigned short* Pf  = (unsigned short*)carve((size_t)EE * 96 * 2);
    unsigned short* Wf0 = (unsigned short*)carve((size_t)1024 * 96 * 2);
    unsigned short* Wf1 = (unsigned short*)carve((size_t)1024 * 96 * 2);
    unsigned short* Wf2 = (unsigned short*)carve((size_t)512 * 96 * 2);
    float* kall = (float*)carve((size_t)NB * 16 * 64 * 4);
    float* V2   = (float*)carve((size_t)NB * 16 * 4 * 64 * 4);
    float* qW   = (float*)carve(192 * 4);
    float* qb2  = (float*)carve(64 * 4);
    float* KtVt = (float*)carve((size_t)NB * 2 * 16 * 64 * 4);

    float* h_final   = (float*)d_out;                 // [M,16]
    float* out_pos   = (float*)d_out + (size_t)MM * 16;
    float* out_batch = (float*)d_out + (size_t)MM * 19;

    // one memset covers aggr (MM*32) + cnt (MM) — adjacent carves
    hipMemsetAsync(aggr, 0, ((size_t)MM * 32 + MM) * sizeof(float), stream);

    k_tokens1<<<64, 128, 0, stream>>>(gt, Wk_w, Wk_b, Wv_w, Wv_b, KtVt);
    k_tokens2<<<NB, 256, 0, stream>>>(KtVt, in_proj_w, in_proj_b, out_w, Wq_w, Wq_b,
                                      kall, V2, qW, qb2);
    k_knn<<<MM / 128, 256, 0, stream>>>(pos, pos_skip, x, x_skip, batch_skip,
                                        hA, out_pos, out_batch);
    k_edge_attn<<<EE / 256, 256, 0, stream>>>(pos_skip, ei, kall, V2, qW, qb2, out_b,
                                              Pf, cnt);
    k_repackAll<<<960, 256, 0, stream>>>(nn_w0, nn_b0, nn_w1, nn_b1, nn_w2, nn_b2,
                                         Wf0, Wf1, Wf2);

    // layer 0: hA -> hB   (update zeroes aggr for layer 1)
    k_conv_mfma<32><<<EE / 128, 256, 0, stream>>>((const uint4*)Pf, hA, ei, (const uint4*)Wf0, aggr);
    k_update<32><<<(MM * 32) / 256, 256, 0, stream>>>(aggr, cnt, hA, root0, bias0, hB);
    // layer 1: hB -> hA   (update zeroes aggr for layer 2)
    k_conv_mfma<32><<<EE / 128, 256, 0, stream>>>((const uint4*)Pf, hB, ei, (const uint4*)Wf1, aggr);
    k_update<32><<<(MM * 32) / 256, 256, 0, stream>>>(aggr, cnt, hB, root1, bias1, hA);
    // layer 2: hA -> d_out
    k_conv_mfma<16><<<EE / 128, 256, 0, stream>>>((const uint4*)Pf, hA, ei, (const uint4*)Wf2, aggr);
    k_update<16><<<(MM * 16) / 256, 256, 0, stream>>>(aggr, cnt, hA, root2, bias2, h_final);
}

// Round 5
// 388.785 us; speedup vs baseline: 3.9224x; 1.0948x over previous
//
#include <hip/hip_runtime.h>
#include <math.h>

#define NB    4        // graphs
#define NN    8192     // coarse nodes
#define MM    65536    // fine nodes
#define EE    131072   // edges
#define NPG   2048     // coarse per graph

typedef short short8 __attribute__((ext_vector_type(8)));
typedef float f32x4  __attribute__((ext_vector_type(4)));

static __device__ inline unsigned short f2b(float f) {
    unsigned u = __float_as_uint(f);
    u += 0x7fffu + ((u >> 16) & 1u);           // RNE
    return (unsigned short)(u >> 16);
}
static __device__ inline unsigned f2b_pack(float a, float b) {
    unsigned x = __float_as_uint(a); x += 0x7fffu + ((x >> 16) & 1u);
    unsigned y = __float_as_uint(b); y += 0x7fffu + ((y >> 16) & 1u);
    return (x >> 16) | (y & 0xffff0000u);
}
static __device__ inline short8 bc8(uint4 v) {
    union { uint4 u; short8 s; } c; c.u = v; return c.s;
}

// ---------------------------------------------------------------------------
// knn_interpolate (k=3): 512 blocks x 256 thr; block = 128 fine nodes.
// ---------------------------------------------------------------------------
__global__ __launch_bounds__(256)
void k_knn(const float* __restrict__ pos, const float* __restrict__ pos_skip,
           const float* __restrict__ x, const float* __restrict__ x_skip,
           const int* __restrict__ batch_skip,
           float* __restrict__ h0, float* __restrict__ out_pos,
           float* __restrict__ out_batch)
{
    __shared__ float4 cp[NPG];                 // 32 KB coarse (x,y,z,|p|^2)
    __shared__ unsigned pk[4][128][3];         // 6 KB partial top-3 keys
    __shared__ float wFin[128][3];
    __shared__ int   iFin[128][3];

    int tid = threadIdx.x;
    int g = blockIdx.x >> 7;                   // 128 blocks per graph
    int cbase = g * NPG;
    for (int c = tid; c < NPG; c += 256) {
        float px = pos[(cbase + c) * 3 + 0];
        float py = pos[(cbase + c) * 3 + 1];
        float pz = pos[(cbase + c) * 3 + 2];
        cp[c] = make_float4(px, py, pz, px * px + py * py + pz * pz);
    }
    __syncthreads();

    int p = tid & 63;                          // node-pair id
    int slice = tid >> 6;                      // candidate slice 0..3
    int fbase = blockIdx.x * 128;
    int f0 = fbase + p, f1 = fbase + 64 + p;
    float fx0 = pos_skip[f0 * 3 + 0], fy0 = pos_skip[f0 * 3 + 1], fz0 = pos_skip[f0 * 3 + 2];
    float fx1 = pos_skip[f1 * 3 + 0], fy1 = pos_skip[f1 * 3 + 1], fz1 = pos_skip[f1 * 3 + 2];
    float fq0 = fx0 * fx0 + fy0 * fy0 + fz0 * fz0;
    float fq1 = fx1 * fx1 + fy1 * fy1 + fz1 * fz1;

    unsigned ka0 = 0xFFFFFFFFu, ka1 = 0xFFFFFFFFu, ka2 = 0xFFFFFFFFu;
    unsigned kb0 = 0xFFFFFFFFu, kb1 = 0xFFFFFFFFu, kb2 = 0xFFFFFFFFu;
    const float4* cps = cp + slice * 512;
#pragma unroll 8
    for (int l = 0; l < 512; ++l) {
        float4 cc = cps[l];
        float s0 = fx0 * cc.x + fy0 * cc.y + fz0 * cc.z;
        float d0 = fmaxf(fq0 + cc.w - 2.f * s0, 0.f);
        unsigned k = (__float_as_uint(d0) & 0xFFFFFE00u) | (unsigned)l;
        unsigned t1 = max(ka0, k); ka0 = min(ka0, k);
        unsigned t2 = max(ka1, t1); ka1 = min(ka1, t1);
        ka2 = min(ka2, t2);
        float s1 = fx1 * cc.x + fy1 * cc.y + fz1 * cc.z;
        float d1 = fmaxf(fq1 + cc.w - 2.f * s1, 0.f);
        unsigned kq = (__float_as_uint(d1) & 0xFFFFFE00u) | (unsigned)l;
        t1 = max(kb0, kq); kb0 = min(kb0, kq);
        t2 = max(kb1, t1); kb1 = min(kb1, t1);
        kb2 = min(kb2, t2);
    }
    pk[slice][p][0] = ka0; pk[slice][p][1] = ka1; pk[slice][p][2] = ka2;
    pk[slice][64 + p][0] = kb0; pk[slice][64 + p][1] = kb1; pk[slice][64 + p][2] = kb2;
    __syncthreads();

    if (tid < 128) {
        int n = tid;
        int f = fbase + n;
        float gx = pos_skip[f * 3 + 0], gy = pos_skip[f * 3 + 1], gz = pos_skip[f * 3 + 2];
        float gq = gx * gx + gy * gy + gz * gz;
        unsigned long long m0 = ~0ull, m1 = ~0ull, m2 = ~0ull;
#pragma unroll
        for (int s = 0; s < 4; ++s)
#pragma unroll
            for (int r = 0; r < 3; ++r) {
                unsigned key = pk[s][n][r];
                int c = s * 512 + (int)(key & 511u);
                float4 cc = cp[c];
                float d = fmaxf(gq + cc.w - 2.f * (gx * cc.x + gy * cc.y + gz * cc.z), 0.f);
                unsigned long long kk = ((unsigned long long)__float_as_uint(d) << 32) | (unsigned)c;
                unsigned long long t1 = m0 > kk ? m0 : kk; m0 = m0 < kk ? m0 : kk;
                unsigned long long t2 = m1 > t1 ? m1 : t1; m1 = m1 < t1 ? m1 : t1;
                m2 = m2 < t2 ? m2 : t2;
            }
        float d0 = __uint_as_float((unsigned)(m0 >> 32));
        float d1 = __uint_as_float((unsigned)(m1 >> 32));
        float d2 = __uint_as_float((unsigned)(m2 >> 32));
        float w0 = 1.f / fmaxf(d0, 1e-16f);
        float w1 = 1.f / fmaxf(d1, 1e-16f);
        float w2 = 1.f / fmaxf(d2, 1e-16f);
        float inv = 1.f / (w0 + w1 + w2);
        wFin[n][0] = w0 * inv; wFin[n][1] = w1 * inv; wFin[n][2] = w2 * inv;
        iFin[n][0] = cbase + (int)(m0 & 2047u);
        iFin[n][1] = cbase + (int)(m1 & 2047u);
        iFin[n][2] = cbase + (int)(m2 & 2047u);
        out_pos[f * 3 + 0] = gx; out_pos[f * 3 + 1] = gy; out_pos[f * 3 + 2] = gz;
        out_batch[f] = (float)batch_skip[f];
    }
    __syncthreads();

    // output fan-out: 2 threads per fine node
    int n2 = tid >> 1, half = tid & 1;
    int f2 = fbase + n2;
    float4* h04 = (float4*)(h0 + (size_t)f2 * 32);
    if (half == 0) {
        const float4* x4 = (const float4*)x;
        float w0 = wFin[n2][0], w1 = wFin[n2][1], w2 = wFin[n2][2];
        int a0 = iFin[n2][0] * 4, a1 = iFin[n2][1] * 4, a2 = iFin[n2][2] * 4;
#pragma unroll
        for (int j = 0; j < 4; ++j) {
            float4 v0 = x4[a0 + j], v1 = x4[a1 + j], v2 = x4[a2 + j];
            float4 r;
            r.x = w0 * v0.x + w1 * v1.x + w2 * v2.x;
            r.y = w0 * v0.y + w1 * v1.y + w2 * v2.y;
            r.z = w0 * v0.z + w1 * v1.z + w2 * v2.z;
            r.w = w0 * v0.w + w1 * v1.w + w2 * v2.w;
            h04[j] = r;
        }
    } else {
        const float4* xs4 = (const float4*)x_skip;
#pragma unroll
        for (int j = 0; j < 4; ++j) h04[4 + j] = xs4[f2 * 4 + j];
    }
}

// ---------------------------------------------------------------------------
// token prep 1: Kt/Vt = gt @ W^T + b + pe   -> KtVt [B][2][16][64]
// ---------------------------------------------------------------------------
__global__ __launch_bounds__(128)
void k_tokens1(const float* __restrict__ gt,
               const float* __restrict__ Wk_w, const float* __restrict__ Wk_b,
               const float* __restrict__ Wv_w, const float* __restrict__ Wv_b,
               float* __restrict__ KtVt)
{
    int b = blockIdx.x >> 4;
    int t = blockIdx.x & 15;
    int which = threadIdx.x >> 6;
    int d = threadIdx.x & 63;
    const float* W = which ? Wv_w : Wk_w;
    const float* bias = which ? Wv_b : Wk_b;
    const float4* row = (const float4*)(gt + (size_t)(b * 16 + t) * 1024);
    const float4* wr = (const float4*)(W + (size_t)d * 1024);
    float acc = 0.f;
    for (int c = 0; c < 256; ++c) {
        float4 a = row[c], w = wr[c];
        acc += a.x * w.x; acc += a.y * w.y; acc += a.z * w.z; acc += a.w * w.w;
    }
    int i2 = d >> 1;
    float dv = expf((float)(2 * i2) * (-0.14391156831212787f)); // -ln(10000)/64
    float ang = (float)t * dv;
    float pe = (d & 1) ? cosf(ang) : sinf(ang);
    KtVt[((size_t)(b * 2 + which) * 16 + t) * 64 + d] = acc + bias[d] + pe;
}

// ---------------------------------------------------------------------------
// token prep 2 (per graph): k/v head proj; V2 = out_w-folded v heads into LDS;
// emits Mfold[g][th=t*4+h][4] = 0.25*(qW,qb2)-folded K (score GEMM collapse)
// and v2f[g] = V2^T in bf16 MFMA A-fragment layout (outdim=m, th=k).
// ---------------------------------------------------------------------------
__global__ __launch_bounds__(256)
void k_tokens2(const float* __restrict__ KtVt,
               const float* __restrict__ in_proj_w, const float* __restrict__ in_proj_b,
               const float* __restrict__ out_w,
               const float* __restrict__ Wq_w, const float* __restrict__ Wq_b,
               float* __restrict__ Mfold, uint4* __restrict__ v2fG)
{
    int b = blockIdx.x;
    int tid = threadIdx.x;
    __shared__ float KtL[1024], VtL[1024], vv[1024], kproj[1024];
    __shared__ float v2L[4096];
    __shared__ float qWs[192], qbs[64];
    for (int idx = tid; idx < 1024; idx += 256) {
        KtL[idx] = KtVt[(size_t)(b * 2 + 0) * 1024 + idx];
        VtL[idx] = KtVt[(size_t)(b * 2 + 1) * 1024 + idx];
    }
    __syncthreads();
    for (int idx = tid; idx < 2048; idx += 256) {
        int which = idx >> 10; int td = idx & 1023; int t = td >> 6; int j = td & 63;
        int r = (which ? 128 : 64) + j;
        const float* w = in_proj_w + (size_t)r * 64;
        const float* src = which ? VtL : KtL;
        float acc = in_proj_b[r];
#pragma unroll 8
        for (int dd = 0; dd < 64; ++dd) acc += src[t * 64 + dd] * w[dd];
        if (which) vv[t * 64 + j] = acc;
        else kproj[t * 64 + j] = acc;
    }
    // qW/qb2 fold (graph-independent, computed by every block; cheap)
    for (int idx = tid; idx < 192; idx += 256) {
        int c = idx >> 6; int j = idx & 63;
        float acc = 0.f;
        for (int dd = 0; dd < 64; ++dd) acc += in_proj_w[(size_t)j * 64 + dd] * Wq_w[dd * 3 + c];
        qWs[c * 64 + j] = acc;
    }
    for (int j = tid; j < 64; j += 256) {
        float acc = in_proj_b[j];
        for (int dd = 0; dd < 64; ++dd) acc += in_proj_w[(size_t)j * 64 + dd] * Wq_b[dd];
        qbs[j] = acc;
    }
    __syncthreads();
    // V2 rows (th = t*4+h) into LDS
    for (int idx = tid; idx < 4096; idx += 256) {
        int jo = idx & 63; int th2 = idx >> 6; int h = th2 & 3; int t = th2 >> 2;
        float acc = 0.f;
#pragma unroll
        for (int dd = 0; dd < 16; ++dd)
            acc += vv[t * 64 + h * 16 + dd] * out_w[(size_t)jo * 64 + h * 16 + dd];
        v2L[(t * 4 + h) * 64 + jo] = acc;
    }
    // Mfold: thread = (th, c)
    {
        int th = tid >> 2, c = tid & 3;
        int t = th >> 2, h = th & 3;
        float acc = 0.f;
#pragma unroll
        for (int dd = h * 16; dd < h * 16 + 16; ++dd) {
            float w = (c == 0) ? qWs[dd] : (c == 1) ? qWs[64 + dd]
                    : (c == 2) ? qWs[128 + dd] : qbs[dd];
            acc += w * kproj[t * 64 + dd];
        }
        Mfold[((size_t)b * 64 + th) * 4 + c] = 0.25f * acc;
    }
    __syncthreads();
    // v2f pack: A-frag bf16, element j: th = step*32 + quad*8 + j, outdim = mi*16 + col
    for (int it = tid; it < 512; it += 256) {
        int lane = it & 63, fi = it >> 6;
        int mi = fi >> 1, step = fi & 1;
        int outd = mi * 16 + (lane & 15);
        int th0 = step * 32 + (lane >> 4) * 8;
        uint4 v;
        v.x = f2b_pack(v2L[(th0 + 0) * 64 + outd], v2L[(th0 + 1) * 64 + outd]);
        v.y = f2b_pack(v2L[(th0 + 2) * 64 + outd], v2L[(th0 + 3) * 64 + outd]);
        v.z = f2b_pack(v2L[(th0 + 4) * 64 + outd], v2L[(th0 + 5) * 64 + outd]);
        v.w = f2b_pack(v2L[(th0 + 6) * 64 + outd], v2L[(th0 + 7) * 64 + outd]);
        v2fG[((size_t)b * 8 + fi) * 64 + lane] = v;
    }
}

// ---------------------------------------------------------------------------
// per-edge cross attention, MFMA PV:
//  scores via Mfold (4 fma per (t,h)); softmax per head; att -> LDS bf16;
//  O^T = V2^T(A-frag, global) x att^T(B-frag, LDS) via 32 mfma;
//  D + out_b -> LDS transpose -> Pf A-frag uint4. Step-2 tail per edge.
// Also fuses dst-degree count.
// ---------------------------------------------------------------------------
__global__ __launch_bounds__(256)
void k_edge_attn(const float* __restrict__ ps, const int* __restrict__ ei,
                 const float* __restrict__ Mfold, const uint4* __restrict__ v2f,
                 const float* __restrict__ ob,
                 unsigned short* __restrict__ Pf, float* __restrict__ cnt)
{
    __shared__ unsigned attL[4 * 64 * 34];     // 34.8 KB; per-wave 64x34-dword slab
    int tid = threadIdx.x;
    int wave = tid >> 6, lane = tid & 63, q = lane >> 4, c15 = lane & 15;
    int g = blockIdx.x >> 7;                   // 128 blocks per graph
    int e = blockIdx.x * 256 + tid;
    int s = ei[e], d = ei[EE + e];
    atomicAdd(&cnt[d], 1.f);
    float sx = ps[s * 3], sy = ps[s * 3 + 1], sz = ps[s * 3 + 2];
    float dx = ps[d * 3], dy = ps[d * 3 + 1], dz = ps[d * 3 + 2];
    float px = dx - sx, py = dy - sy, pz = dz - sz;
    float ex = 0.5f * (dx + sx), ey = 0.5f * (dy + sy), ez = 0.5f * (dz + sz);

    // scores via Mfold (uniform address -> scalar loads)
    const float4* Mg = (const float4*)Mfold + (size_t)g * 64;
    float sc[64];
#pragma unroll
    for (int th = 0; th < 64; ++th) {
        float4 m = Mg[th];
        sc[th] = ex * m.x + ey * m.y + ez * m.z + m.w;
    }
    // softmax per head over 16 tokens (th = t*4+h)
#pragma unroll
    for (int h = 0; h < 4; ++h) {
        float mx = sc[h];
#pragma unroll
        for (int t = 1; t < 16; ++t) mx = fmaxf(mx, sc[t * 4 + h]);
        float ssum = 0.f;
#pragma unroll
        for (int t = 0; t < 16; ++t) {
            float eo = expf(sc[t * 4 + h] - mx);
            sc[t * 4 + h] = eo; ssum += eo;
        }
        float inv = 1.f / ssum;
#pragma unroll
        for (int t = 0; t < 16; ++t) sc[t * 4 + h] *= inv;
    }
    // att -> LDS bf16 (row = edge-in-wave, 32 dwords + pad2)
    unsigned* slab = attL + wave * 64 * 34;
#pragma unroll
    for (int k = 0; k < 16; ++k) {
        uint2 v;
        v.x = f2b_pack(sc[4 * k + 0], sc[4 * k + 1]);
        v.y = f2b_pack(sc[4 * k + 2], sc[4 * k + 3]);
        *(uint2*)&slab[lane * 34 + 2 * k] = v;
    }
    __syncthreads();

    uint4 v2a[4][2];
#pragma unroll
    for (int mi = 0; mi < 4; ++mi)
#pragma unroll
        for (int st = 0; st < 2; ++st)
            v2a[mi][st] = v2f[((size_t)g * 8 + mi * 2 + st) * 64 + lane];

    f32x4 acc[4][4];
#pragma unroll
    for (int mi = 0; mi < 4; ++mi)
#pragma unroll
        for (int nt = 0; nt < 4; ++nt) acc[mi][nt] = (f32x4){0.f, 0.f, 0.f, 0.f};

#pragma unroll
    for (int nt = 0; nt < 4; ++nt) {
        const unsigned* rb = &slab[(nt * 16 + c15) * 34];
        uint4 b0 = *(const uint4*)&rb[q * 4];
        uint4 b1 = *(const uint4*)&rb[16 + q * 4];
#pragma unroll
        for (int mi = 0; mi < 4; ++mi) {
            acc[mi][nt] = __builtin_amdgcn_mfma_f32_16x16x32_bf16(bc8(v2a[mi][0]), bc8(b0), acc[mi][nt], 0, 0, 0);
            acc[mi][nt] = __builtin_amdgcn_mfma_f32_16x16x32_bf16(bc8(v2a[mi][1]), bc8(b1), acc[mi][nt], 0, 0, 0);
        }
    }
    __syncthreads();

    // D + out_b -> O (bf16) over the same slab: row = edge-in-wave, dword = outdim/2
    float4 obv[4];
#pragma unroll
    for (int mi = 0; mi < 4; ++mi) obv[mi] = *(const float4*)(ob + mi * 16 + q * 4);
#pragma unroll
    for (int mi = 0; mi < 4; ++mi)
#pragma unroll
        for (int nt = 0; nt < 4; ++nt) {
            f32x4 a = acc[mi][nt];
            uint2 v;
            v.x = f2b_pack(a[0] + obv[mi].x, a[1] + obv[mi].y);
            v.y = f2b_pack(a[2] + obv[mi].z, a[3] + obv[mi].w);
            *(uint2*)&slab[(nt * 16 + c15) * 34 + mi * 8 + q * 2] = v;
        }
    __syncthreads();

    // Pf A-frag: lane (q,c15) reads its short8 (k = st*32 + q*8 + j) for each edge tile
    uint4* Pf4 = (uint4*)Pf;
#pragma unroll
    for (int et = 0; et < 4; ++et) {
        int etg = blockIdx.x * 16 + wave * 4 + et;
#pragma unroll
        for (int st = 0; st < 2; ++st) {
            uint4 w = *(const uint4*)&slab[(et * 16 + c15) * 34 + st * 16 + q * 4];
            Pf4[((size_t)etg * 3 + st) * 64 + lane] = w;
        }
    }
    // step 2 tail (k = 64..95): (px,py,pz,1, zeros) for own edge
    int et2 = e >> 4, eL = e & 15;
    size_t tb = ((size_t)(et2 * 3 + 2) * 64 + 0 * 16 + eL) * 8;
    uint2 t0; t0.x = f2b_pack(px, py); t0.y = f2b_pack(pz, 1.0f);
    *(uint2*)(Pf + tb) = t0;
    uint2 z2; z2.x = 0u; z2.y = 0u;
    *(uint2*)(Pf + tb + 4) = z2;
#pragma unroll
    for (int quad = 1; quad < 4; ++quad) {
        size_t zb = ((size_t)(et2 * 3 + 2) * 64 + quad * 16 + eL) * 8;
        uint4 z4; z4.x = 0u; z4.y = 0u; z4.z = 0u; z4.w = 0u;
        *(uint4*)(Pf + zb) = z4;
    }
}

// ---------------------------------------------------------------------------
// fused repack of all 3 layers' nn_w/nn_b -> bf16 B-fragment streams
// ---------------------------------------------------------------------------
static __device__ inline void repack_one(const float* __restrict__ nw,
                                         const float* __restrict__ nb,
                                         unsigned short* __restrict__ Wf, int idx)
{
    int jj = idx & 7;
    int lane = (idx >> 3) & 63;
    int rest = idx >> 9;
    int s = rest % 3;
    int jt = rest / 3;
    int j = jt * 16 + (lane & 15);
    int k = s * 32 + (lane >> 4) * 8 + jj;
    float v;
    if (k < 64)       v = nw[(size_t)j * 67 + 3 + k];
    else if (k < 67)  v = nw[(size_t)j * 67 + (k - 64)];
    else if (k == 67) v = nb[j];
    else              v = 0.f;
    Wf[idx] = f2b(v);
}

__global__ __launch_bounds__(256)
void k_repackAll(const float* __restrict__ nw0, const float* __restrict__ nb0,
                 const float* __restrict__ nw1, const float* __restrict__ nb1,
                 const float* __restrict__ nw2, const float* __restrict__ nb2,
                 unsigned short* __restrict__ Wf0, unsigned short* __restrict__ Wf1,
                 unsigned short* __restrict__ Wf2)
{
    int idx = blockIdx.x * 256 + threadIdx.x;
    if (idx < 98304)        repack_one(nw0, nb0, Wf0, idx);
    else if (idx < 196608)  repack_one(nw1, nb1, Wf1, idx - 98304);
    else                    repack_one(nw2, nb2, Wf2, idx - 196608);
}

// ---------------------------------------------------------------------------
// MFMA edge pass: per wave 32 edges (2 A-frag sets), loop 2*CO j-tiles:
//   we_tile = relu(P @ W^T) via 3x mfma_16x16x32_bf16; msg += h[src][i]*we;
// scatter atomicAdd at the end. No __syncthreads in the j-loop.
// ---------------------------------------------------------------------------
template<int CO>
__global__ __launch_bounds__(256, 4)
void k_conv_mfma(const uint4* __restrict__ Pf, const float* __restrict__ hin,
                 const int* __restrict__ ei, const uint4* __restrict__ Wf,
                 float* __restrict__ aggr)
{
    constexpr int JT = 2 * CO;          // 64 (CO=32) or 32 (CO=16)
    constexpr int NPAR = CO / 16;       // 2 or 1
    __shared__ float hL[128 * 36];      // stride 36 floats
    __shared__ int sL[128];
    __shared__ int dL[128];

    int tid = threadIdx.x;
    int e0 = blockIdx.x * 128;
    if (tid < 128) sL[tid] = ei[e0 + tid];
    else           dL[tid - 128] = ei[EE + e0 + (tid - 128)];
    __syncthreads();
    for (int idx = tid; idx < 1024; idx += 256) {
        int row = idx >> 3, c = idx & 7;
        const float4* hr = (const float4*)(hin + (size_t)sL[row] * 32);
        *(float4*)&hL[row * 36 + c * 4] = hr[c];
    }
    __syncthreads();

    int wave = tid >> 6, lane = tid & 63, quad = lane >> 4, col = lane & 15;

    uint4 a[2][3];
    int et0 = blockIdx.x * 8 + wave * 2;
#pragma unroll
    for (int st = 0; st < 2; ++st)
#pragma unroll
        for (int s = 0; s < 3; ++s)
            a[st][s] = Pf[((size_t)(et0 + st) * 3 + s) * 64 + lane];

    float msg[2][NPAR][4];
#pragma unroll
    for (int st = 0; st < 2; ++st)
#pragma unroll
        for (int p = 0; p < NPAR; ++p)
#pragma unroll
            for (int r = 0; r < 4; ++r) msg[st][p][r] = 0.f;

#pragma unroll 2
    for (int jt = 0; jt < JT; ++jt) {
        uint4 b0 = Wf[((size_t)jt * 3 + 0) * 64 + lane];
        uint4 b1 = Wf[((size_t)jt * 3 + 1) * 64 + lane];
        uint4 b2 = Wf[((size_t)jt * 3 + 2) * 64 + lane];
        int i   = (CO == 32) ? (jt >> 1) : jt;
        int par = (CO == 32) ? (jt & 1) : 0;
#pragma unroll
        for (int st = 0; st < 2; ++st) {
            f32x4 c = {0.f, 0.f, 0.f, 0.f};
            c = __builtin_amdgcn_mfma_f32_16x16x32_bf16(bc8(a[st][0]), bc8(b0), c, 0, 0, 0);
            c = __builtin_amdgcn_mfma_f32_16x16x32_bf16(bc8(a[st][1]), bc8(b1), c, 0, 0, 0);
            c = __builtin_amdgcn_mfma_f32_16x16x32_bf16(bc8(a[st][2]), bc8(b2), c, 0, 0, 0);
#pragma unroll
            for (int r = 0; r < 4; ++r) {
                float hv = hL[(wave * 32 + st * 16 + quad * 4 + r) * 36 + i];
                msg[st][par][r] += hv * fmaxf(c[r], 0.f);
            }
        }
    }

#pragma unroll
    for (int st = 0; st < 2; ++st)
#pragma unroll
        for (int r = 0; r < 4; ++r) {
            int dv = dL[wave * 32 + st * 16 + quad * 4 + r];
#pragma unroll
            for (int p = 0; p < NPAR; ++p)
                atomicAdd(&aggr[(size_t)dv * CO + p * 16 + col], msg[st][p][r]);
        }
}

// ---------------------------------------------------------------------------
// node update: h' = relu(aggr/cnt + h @ root + bias); zeroes aggr for the
// next layer's atomic pass (replaces per-layer memsets).
// ---------------------------------------------------------------------------
template<int CO>
__global__ __launch_bounds__(256)
void k_update(float* __restrict__ aggr, const float* __restrict__ cnt,
              const float* __restrict__ hin, const float* __restrict__ root,
              const float* __restrict__ bias, float* __restrict__ hout)
{
    __shared__ float rL[32 * CO];
    __shared__ float bL[CO];
    int tid = threadIdx.x;
    for (int idx = tid; idx < 32 * CO; idx += 256) rL[idx] = root[idx];
    if (tid < CO) bL[tid] = bias[tid];
    __syncthreads();
    int gid = blockIdx.x * 256 + tid;
    int v = gid / CO;
    int o = gid % CO;
    float acc = aggr[gid] / fmaxf(cnt[v], 1.f) + bL[o];
    aggr[gid] = 0.f;                    // prep next layer's scatter
    const float* hr = hin + (size_t)v * 32;
#pragma unroll
    for (int i = 0; i < 32; ++i) acc += hr[i] * rL[i * CO + o];
    hout[gid] = fmaxf(acc, 0.f);
}

// ---------------------------------------------------------------------------
extern "C" void kernel_launch(void* const* d_in, const int* in_sizes, int n_in,
                              void* d_out, int out_size, void* d_ws, size_t ws_size,
                              hipStream_t stream)
{
    const float* x          = (const float*)d_in[0];
    const float* pos        = (const float*)d_in[1];
    const float* x_skip     = (const float*)d_in[3];
    const float* pos_skip   = (const float*)d_in[4];
    const int*   batch_skip = (const int*)  d_in[5];
    const int*   ei         = (const int*)  d_in[6];
    const float* gt         = (const float*)d_in[7];
    const float* Wq_w       = (const float*)d_in[8];
    const float* Wq_b       = (const float*)d_in[9];
    const float* Wk_w       = (const float*)d_in[10];
    const float* Wk_b       = (const float*)d_in[11];
    const float* Wv_w       = (const float*)d_in[12];
    const float* Wv_b       = (const float*)d_in[13];
    const float* in_proj_w  = (const float*)d_in[14];
    const float* in_proj_b  = (const float*)d_in[15];
    const float* out_w      = (const float*)d_in[16];
    const float* out_b      = (const float*)d_in[17];
    const float* nn_w0 = (const float*)d_in[18]; const float* nn_b0 = (const float*)d_in[19];
    const float* root0 = (const float*)d_in[20]; const float* bias0 = (const float*)d_in[21];
    const float* nn_w1 = (const float*)d_in[22]; const float* nn_b1 = (const float*)d_in[23];
    const float* root1 = (const float*)d_in[24]; const float* bias1 = (const float*)d_in[25];
    const float* nn_w2 = (const float*)d_in[26]; const float* nn_b2 = (const float*)d_in[27];
    const float* root2 = (const float*)d_in[28]; const float* bias2 = (const float*)d_in[29];

    char* wsb = (char*)d_ws;
    size_t off = 0;
    auto carve = [&](size_t bytes) { char* p = wsb + off; off += (bytes + 255) & ~(size_t)255; return p; };
    float* aggr = (float*)carve((size_t)MM * 32 * 4);   // aggr then cnt: one memset
    float* cnt  = (float*)carve((size_t)MM * 4);
    float* hA   = (float*)carve((size_t)MM * 32 * 4);
    float* hB   = (float*)carve((size_t)MM * 32 * 4);
    unsigned short* Pf  = (unsigned short*)carve((size_t)EE * 96 * 2);
    unsigned short* Wf0 = (unsigned short*)carve((size_t)1024 * 96 * 2);
    unsigned short* Wf1 = (unsigned short*)carve((size_t)1024 * 96 * 2);
    unsigned short* Wf2 = (unsigned short*)carve((size_t)512 * 96 * 2);
    float* Mfold = (float*)carve((size_t)NB * 64 * 4 * 4);
    uint4* v2f   = (uint4*)carve((size_t)NB * 8 * 64 * 16);
    float* KtVt  = (float*)carve((size_t)NB * 2 * 16 * 64 * 4);

    float* h_final   = (float*)d_out;                 // [M,16]
    float* out_pos   = (float*)d_out + (size_t)MM * 16;
    float* out_batch = (float*)d_out + (size_t)MM * 19;

    // one memset covers aggr (MM*32) + cnt (MM) — adjacent carves
    hipMemsetAsync(aggr, 0, ((size_t)MM * 32 + MM) * sizeof(float), stream);

    k_tokens1<<<64, 128, 0, stream>>>(gt, Wk_w, Wk_b, Wv_w, Wv_b, KtVt);
    k_tokens2<<<NB, 256, 0, stream>>>(KtVt, in_proj_w, in_proj_b, out_w, Wq_w, Wq_b,
                                      Mfold, v2f);
    k_knn<<<MM / 128, 256, 0, stream>>>(pos, pos_skip, x, x_skip, batch_skip,
                                        hA, out_pos, out_batch);
    k_edge_attn<<<EE / 256, 256, 0, stream>>>(pos_skip, ei, Mfold, v2f, out_b,
                                              Pf, cnt);
    k_repackAll<<<960, 256, 0, stream>>>(nn_w0, nn_b0, nn_w1, nn_b1, nn_w2, nn_b2,
                                         Wf0, Wf1, Wf2);

    // layer 0: hA -> hB   (update zeroes aggr for layer 1)
    k_conv_mfma<32><<<EE / 128, 256, 0, stream>>>((const uint4*)Pf, hA, ei, (const uint4*)Wf0, aggr);
    k_update<32><<<(MM * 32) / 256, 256, 0, stream>>>(aggr, cnt, hA, root0, bias0, hB);
    // layer 1: hB -> hA   (update zeroes aggr for layer 2)
    k_conv_mfma<32><<<EE / 128, 256, 0, stream>>>((const uint4*)Pf, hB, ei, (const uint4*)Wf1, aggr);
    k_update<32><<<(MM * 32) / 256, 256, 0, stream>>>(aggr, cnt, hB, root1, bias1, hA);
    // layer 2: hA -> d_out
    k_conv_mfma<16><<<EE / 128, 256, 0, stream>>>((const uint4*)Pf, hA, ei, (const uint4*)Wf2, aggr);
    k_update<16><<<(MM * 16) / 256, 256, 0, stream>>>(aggr, cnt, hA, root2, bias2, h_final);
}